// Round 4
// baseline (1507.453 us; speedup 1.0000x reference)
//
#include <hip/hip_runtime.h>
#include <hip/hip_cooperative_groups.h>

namespace cg = cooperative_groups;

#define G_ 100
#define T_ 24
#define NSC 128
#define BATCH 8
#define NITER 40
#define NBLK (BATCH*T_)     // 192 WGs: one (batch,t) per WG
#define NTHR 512            // 8 waves -> 2 waves/SIMD for latency hiding
#define GMAX 13

__device__ __forceinline__ float gload(const float* p){
  return __hip_atomic_load(p, __ATOMIC_RELAXED, __HIP_MEMORY_SCOPE_AGENT);
}
__device__ __forceinline__ void gstore(float* p, float v){
  __hip_atomic_store(p, v, __ATOMIC_RELAXED, __HIP_MEMORY_SCOPE_AGENT);
}
__device__ __forceinline__ unsigned gloadu(const unsigned* p){
  return __hip_atomic_load(p, __ATOMIC_RELAXED, __HIP_MEMORY_SCOPE_AGENT);
}
__device__ __forceinline__ void gstoreu(unsigned* p, unsigned v){
  __hip_atomic_store(p, v, __ATOMIC_RELAXED, __HIP_MEMORY_SCOPE_AGENT);
}

// 8-wave block reductions
__device__ __forceinline__ void blockReduce2(float& a, float& b, float* sR){
#pragma unroll
  for (int off=32; off; off>>=1){ a+=__shfl_down(a,off,64); b+=__shfl_down(b,off,64); }
  const int w = threadIdx.x>>6;
  __syncthreads();
  if ((threadIdx.x&63)==0){ sR[w]=a; sR[8+w]=b; }
  __syncthreads();
  a=0.f; b=0.f;
#pragma unroll
  for (int i=0;i<8;++i){ a+=sR[i]; b+=sR[8+i]; }
}
__device__ __forceinline__ void blockReduce3(float& a, float& b, float& c, float* sR){
#pragma unroll
  for (int off=32; off; off>>=1){
    a+=__shfl_down(a,off,64); b+=__shfl_down(b,off,64); c+=__shfl_down(c,off,64);
  }
  const int w = threadIdx.x>>6;
  __syncthreads();
  if ((threadIdx.x&63)==0){ sR[w]=a; sR[8+w]=b; sR[16+w]=c; }
  __syncthreads();
  a=0.f; b=0.f; c=0.f;
#pragma unroll
  for (int i=0;i<8;++i){ a+=sR[i]; b+=sR[8+i]; c+=sR[16+i]; }
}

// wave0 polls the 24 per-slice epoch flags; everyone else waits at the barrier.
// all cross-WG data moves via agent-scope (cache-bypassing) accesses, so only
// wave0 needs the acquire fence.
__device__ __forceinline__ void waitEpoch(const unsigned* fl, unsigned tgt, int tid, int lane){
  if (tid < 64){
    for (;;){
      unsigned f = (lane < T_) ? gloadu(&fl[lane]) : tgt;
      if (__ballot(f < tgt) == 0ull) break;
      __builtin_amdgcn_s_sleep(1);
    }
    __builtin_amdgcn_fence(__ATOMIC_ACQUIRE, "agent");
  }
  __syncthreads();
}

__global__ __launch_bounds__(NTHR, 2) void dro_kernel(
    const float* __restrict__ forecast, const float* __restrict__ omega,
    const float* __restrict__ om_min, const float* __restrict__ om_max,
    const float* __restrict__ eps_in, const float* __restrict__ pmin_g,
    const float* __restrict__ pmax_g, const float* __restrict__ bG,
    const float* __restrict__ cG, float* __restrict__ out, float* __restrict__ ws)
{
  constexpr float LR=2e-4f, VOLL=1000.f, VOSP=50.f, TWO_RHO=20.f, INVN=1.f/128.f;
  const int blk=blockIdx.x;
  const int b=blk&7;
  const int t_own=blk>>3;
  const int tid=threadIdx.x, wave=tid>>6, lane=tid&63;
  const int gcnt  = (wave<4)? 13 : 12;
  const int gbase = (wave<4)? wave*13 : 52+(wave-4)*12;

  __shared__ float sRu[G_], sRd[G_];
  __shared__ float sP[G_], sduM[G_], sddM[G_], sdum[G_], sddm[G_];
  __shared__ float sAccU[G_], sAccD[G_];
  __shared__ float sB[G_], sPmin[G_], sPmax[G_], sC[G_];
  __shared__ float sLS[NSC], sSP[NSC], sOm[NSC];
  __shared__ float sGQ[NSC], sR220[NSC];
  __shared__ float sQn[NSC], sDM[NSC], sDm[NSC], sS2[NSC];
  __shared__ float sQp[NSC*9], sSp[NSC*9];     // [n][wave] stride 9 (conflict-free)
  __shared__ float sQnP[NTHR];
  __shared__ float sRed[24];
  __shared__ float sScal[8];   // 0..2: r3,r4,rP ; 3..6: LSM,SPM,LSm,SPm

  float* QNP = ws;                          // [3][B][24][128]
  float* PP  = ws + 73728;                  // [3][B][24][128] (first 100 used)
  float* QS  = ws + 147456;                 // [3][B][32][2]
  float* GAM = ws + 148992;                 // [3][16]
  float* ST1 = ws + 149040;                 // [B][32]
  unsigned* FLG = (unsigned*)(ws + 149296); // [B][32]

  const float epsv  = eps_in[b];
  const float omaxT = om_max[b*T_ + t_own];
  const float ominT = om_min[b*T_ + t_own];
  const float fctT  = forecast[b*T_ + t_own];
  const unsigned* flB = FLG + b*32;

  float duA[GMAX], duB[GMAX], ddA[GMAX], ddB[GMAX];
  float rtuR[GMAX], rtdR[GMAX];

  // ---------------- init ----------------
  if (tid<G_){
    sB[tid]=bG[tid]; sPmin[tid]=pmin_g[tid]; sPmax[tid]=pmax_g[tid]; sC[tid]=cG[tid];
    sRu[tid]=0.f; sRd[tid]=0.f;
    sduM[tid]=0.f; sddM[tid]=0.f; sdum[tid]=0.f; sddm[tid]=0.f;
  }
  if (tid<NSC){
    const int n=tid;
    sLS[n]=0.f; sSP[n]=0.f; sS2[n]=0.f;
    sOm[n]=omega[(b*NSC+n)*T_+t_own];
    float dM=0.f,dm=0.f;
    for (int t=0;t<T_;++t){
      float o=omega[(b*NSC+n)*T_+t];
      dM+=om_max[b*T_+t]-o; dm+=o-om_min[b*T_+t];
    }
    sDM[n]=dM; sDm[n]=dm;
  }
  if (tid==0){ sScal[3]=0.f; sScal[4]=0.f; sScal[5]=0.f; sScal[6]=0.f; }
  __syncthreads();
#pragma unroll
  for (int j=0;j<GMAX;++j){
    duA[j]=0.f; duB[j]=0.f; ddA[j]=0.f; ddB[j]=0.f;
    if (j<gcnt){ const int g=gbase+j; rtuR[j]=2.f*sB[g]; rtdR[j]=0.5f*sB[g]; }
    else { rtuR[j]=0.f; rtdR[j]=0.f; }
  }
  {
    float p0=0.f;
    if (tid<G_){
      p0=0.5f*(sPmin[tid]+sPmax[tid]);
      sP[tid]=p0;
      gstore(&PP[b*3072 + t_own*NSC + tid], p0);
    }
    if (tid<NSC) gstore(&QNP[b*3072 + t_own*NSC + tid], 0.f);
    if (tid<2)   gstore(&QS[b*64 + t_own*2 + tid], 0.f);
    if (t_own==0 && tid==0) gstore(&GAM[b], 0.f);
    float rp=p0, dum0=0.f;
    blockReduce2(rp,dum0,sRed);
    if (tid==0){
      sScal[0]=-omaxT; sScal[1]=-ominT; sScal[2]=rp-fctT;
      gstoreu((unsigned*)&FLG[b*32+t_own], 1u);
    }
  }
  __builtin_amdgcn_fence(__ATOMIC_RELEASE, "agent");
  cg::this_grid().sync();

  for (int k=0;k<=NITER;++k){
    waitEpoch(flB, (unsigned)(k+1), tid, lane);

    const int rb = k%3, wb = (k+1)%3;
    const float* qnpR = QNP + rb*24576 + b*3072;
    const float* ppR  = PP  + rb*24576 + b*3072;
    const float* qsR  = QS  + rb*512   + b*64;
    float* qnpW = QNP + wb*24576 + b*3072 + t_own*NSC;
    float* ppW  = PP  + wb*24576 + b*3072 + t_own*NSC;
    float* qsW  = QS  + wb*512   + b*64  + t_own*2;

    const float gamma = gload(&GAM[rb*16 + b]);
    float pm1=0.f, pp1=0.f;
    if (tid<G_){
      if (t_own>0)     pm1 = gload(&ppR[(t_own-1)*NSC + tid]);
      if (t_own<T_-1)  pp1 = gload(&ppR[(t_own+1)*NSC + tid]);
    }
    {
      const int n = tid&127, sb0 = (tid>>7)*6;
      float q=0.f;
#pragma unroll
      for (int s=0;s<6;++s) q += gload(&qnpR[(sb0+s)*NSC + n]);
      sQnP[tid]=q;
    }
    float Qmax = (tid<T_)? gload(&qsR[tid*2])   : 0.f;
    float Qmin = (tid<T_)? gload(&qsR[tid*2+1]) : 0.f;
    blockReduce2(Qmax,Qmin,sRed);      // its syncs also publish sQnP
    if (tid<NSC) sQn[tid]=sQnP[tid]+sQnP[tid+128]+sQnP[tid+256]+sQnP[tid+384];

    if (k==NITER){  // ---------------- final: phi + outputs ----------------
      if (tid<NSC){
        const int n=tid;
        const float m1=Qmax-gamma*sDM[n], m2=Qmin-gamma*sDm[n];
        const float ph=fmaxf(sQn[n],fmaxf(m1,m2));
        sQn[n]=ph;
        if (t_own==0) out[76800 + b*NSC + n]=ph;
      }
      float st=0.f, dum0=0.f;
      if (tid<G_){
        const int g=tid;
        const float Pv=sP[g];
        const float costv=sB[g]*Pv+sC[g];
        st=costv + 0.05f*sB[g]*sRu[g] + 0.02f*sB[g]*sRd[g];
        const int o=b*2400 + g*T_ + t_own;
        out[o]=Pv;
        out[19200+o]=sRu[g];
        out[38400+o]=sRd[g];
        out[57600+o]=costv;
      }
      blockReduce2(st,dum0,sRed);
      if (tid==0) gstore(&ST1[b*32+t_own], st);
      if (t_own==0 && tid==0) out[77824+b]=gamma;
      __builtin_amdgcn_fence(__ATOMIC_RELEASE, "agent");
      __syncthreads();
      if (tid==0) gstoreu((unsigned*)&FLG[b*32+t_own], (unsigned)(NITER+2));
      if (t_own==0){
        waitEpoch(flB, (unsigned)(NITER+2), tid, lane);
        float pm = (tid<NSC)? sQn[tid] : 0.f;
        float s1 = (tid<T_)? gload(&ST1[b*32+tid]) : 0.f;
        blockReduce2(pm,s1,sRed);
        if (tid==0) out[77832+b] = s1 + pm*INVN + epsv*gamma;
      }
      break;
    }

    // ---- weights (balanced_eq ties) + LS/SP update (tid<128) ----
    float g1l=0.f,g2l=0.f,sgl=0.f;
    if (tid<NSC){
      const int n=tid;
      const float Qn=sQn[n];
      const float m1=Qmax-gamma*sDM[n], m2=Qmin-gamma*sDm[n];
      const float inner=fmaxf(m1,m2), ph=fmaxf(Qn,inner);
      const float gQn=(Qn==ph?1.f:0.f)/((inner==ph)?2.f:1.f);
      const float gIn=(inner==ph?1.f:0.f)/((Qn==ph)?2.f:1.f);
      const float gm1=gIn*(m1==inner?1.f:0.f)/((m2==inner)?2.f:1.f);
      const float gm2=gIn*(m2==inner?1.f:0.f)/((m1==inner)?2.f:1.f);
      const float gq=gQn*INVN;
      sGQ[n]=gq;
      g1l=gm1; g2l=gm2; sgl=gm1*sDM[n]+gm2*sDm[n];
      const float r2=sS2[n]+sLS[n]-sSP[n]-sOm[n];
      const float r220=TWO_RHO*r2;
      sR220[n]=r220;
      sLS[n]=fmaxf(sLS[n]-LR*(gq*VOLL+r220),0.f);
      sSP[n]=fmaxf(sSP[n]-LR*(gq*VOSP-r220),0.f);
    }
    float S1s=g1l,S2s=g2l,Sg=sgl;
    blockReduce3(S1s,S2s,Sg,sRed);   // syncs publish sGQ/sR220/new LS,SP

    // ---- pass A: register-resident d update + fused produce partials ----
    const float gqA=sGQ[lane],    r220A=sR220[lane];
    const float gqB=sGQ[lane+64], r220B=sR220[lane+64];
    float qvA=0.f,qvB=0.f,svA=0.f,svB=0.f;
#pragma unroll
    for (int j=0;j<GMAX;++j){
      if (j<gcnt){
        const int g=gbase+j;
        const float ru=sRu[g], rd=sRd[g];     // LDS broadcast reads
        const float r7A=fmaxf(duA[j]-ru,0.f), r8A=fmaxf(ddA[j]-rd,0.f);
        const float r7B=fmaxf(duB[j]-ru,0.f), r8B=fmaxf(ddB[j]-rd,0.f);
        float aU=r7A+r7B, aD=r8A+r8B;
#pragma unroll
        for (int off=32; off; off>>=1){ aU+=__shfl_xor(aU,off,64); aD+=__shfl_xor(aD,off,64); }
        if (lane==0){ sAccU[g]=aU; sAccD[g]=aD; }
        const float rtu=rtuR[j], rtd=rtdR[j];
        duA[j]=fmaxf(duA[j]-LR*(gqA*rtu+(r220A+TWO_RHO*r7A)),0.f);
        ddA[j]=fmaxf(ddA[j]-LR*(gqA*rtd+(TWO_RHO*r8A-r220A)),0.f);
        duB[j]=fmaxf(duB[j]-LR*(gqB*rtu+(r220B+TWO_RHO*r7B)),0.f);
        ddB[j]=fmaxf(ddB[j]-LR*(gqB*rtd+(TWO_RHO*r8B-r220B)),0.f);
        qvA+=rtu*duA[j]+rtd*ddA[j];  svA+=duA[j]-ddA[j];
        qvB+=rtu*duB[j]+rtd*ddB[j];  svB+=duB[j]-ddB[j];
      }
    }
    sQp[lane*9+wave]=qvA;      sSp[lane*9+wave]=svA;
    sQp[(lane+64)*9+wave]=qvB; sSp[(lane+64)*9+wave]=svB;
    __syncthreads();

    // ---- combine produce partials (waves 4-5) | pass B (tid<100) ----
    if (tid>=256 && tid<384){
      const int n=tid-256;
      float q=0.f,s=0.f;
#pragma unroll
      for (int w=0;w<8;++w){ q+=sQp[n*9+w]; s+=sSp[n*9+w]; }
      sS2[n]=s;
      q += VOLL*sLS[n]+VOSP*sSP[n];
      gstore(&qnpW[n], q);
    }
    const float r3=sScal[0], r4=sScal[1], rP=sScal[2];
    float pQx=0.f,pQn2=0.f,pr3=0.f,pr4=0.f,pP=0.f;
    if (tid<G_){
      const int g=tid;
      const float rupS=sAccU[g], rdnS=sAccD[g];
      const float Pold=sP[g], ru=sRu[g], rd=sRd[g];
      const float duMo=sduM[g], ddMo=sddM[g], dumo=sdum[g], ddmo=sddm[g];
      const float r5 =fmaxf(Pold+ru-sPmax[g],0.f);
      const float r6 =fmaxf(sPmin[g]-Pold+rd,0.f);
      const float r9 =fmaxf(duMo-ru,0.f), r10=fmaxf(ddMo-rd,0.f);
      const float r11=fmaxf(dumo-ru,0.f), r12=fmaxf(ddmo-rd,0.f);
      const float rampg=sPmax[g];
      float gP=sB[g]+TWO_RHO*(rP+r5-r6);
      if (t_own>0){
        const float dp=Pold-pm1;
        gP+=TWO_RHO*fmaxf(fabsf(dp)-rampg,0.f)*(dp>=0.f?1.f:-1.f);
      }
      if (t_own<T_-1){
        const float dq=pp1-Pold;
        gP-=TWO_RHO*fmaxf(fabsf(dq)-rampg,0.f)*(dq>=0.f?1.f:-1.f);
      }
      const float Pn=fminf(fmaxf(Pold-LR*gP,sPmin[g]),sPmax[g]);
      sP[g]=Pn; gstore(&ppW[g],Pn);
      const float rtuB=2.f*sB[g], rtdB=0.5f*sB[g];
      sRu[g]=fmaxf(ru-LR*(0.05f*sB[g]+TWO_RHO*(r5-rupS-r9-r11)),0.f);
      sRd[g]=fmaxf(rd-LR*(0.02f*sB[g]+TWO_RHO*(r6-rdnS-r10-r12)),0.f);
      const float duMn=fmaxf(duMo-LR*(INVN*S1s*rtuB+TWO_RHO*( r3+r9 )),0.f);
      const float ddMn=fmaxf(ddMo-LR*(INVN*S1s*rtdB+TWO_RHO*(-r3+r10)),0.f);
      const float dumn=fmaxf(dumo-LR*(INVN*S2s*rtuB+TWO_RHO*( r4+r11)),0.f);
      const float ddmn=fmaxf(ddmo-LR*(INVN*S2s*rtdB+TWO_RHO*(-r4+r12)),0.f);
      sduM[g]=duMn; sddM[g]=ddMn; sdum[g]=dumn; sddm[g]=ddmn;
      pQx=rtuB*duMn+rtdB*ddMn; pQn2=rtuB*dumn+rtdB*ddmn;
      pr3=duMn-ddMn; pr4=dumn-ddmn; pP=Pn;
    }
    blockReduce3(pQx,pQn2,pr3,sRed);
    blockReduce2(pr4,pP,sRed);
    if (tid==0){
      const float LSMn=fmaxf(sScal[3]-LR*(INVN*S1s*VOLL+TWO_RHO*r3),0.f);
      const float SPMn=fmaxf(sScal[4]-LR*(INVN*S1s*VOSP-TWO_RHO*r3),0.f);
      const float LSmn=fmaxf(sScal[5]-LR*(INVN*S2s*VOLL+TWO_RHO*r4),0.f);
      const float SPmn=fmaxf(sScal[6]-LR*(INVN*S2s*VOSP-TWO_RHO*r4),0.f);
      sScal[3]=LSMn; sScal[4]=SPMn; sScal[5]=LSmn; sScal[6]=SPmn;
      gstore(&qsW[0], pQx + VOLL*LSMn + VOSP*SPMn);
      gstore(&qsW[1], pQn2 + VOLL*LSmn + VOSP*SPmn);
      sScal[0]=pr3 + LSMn - SPMn - omaxT;
      sScal[1]=pr4 + LSmn - SPmn - ominT;
      sScal[2]=pP - fctT;
    }
    if (t_own==0 && tid==448)
      gstore(&GAM[wb*16+b], fmaxf(gamma-LR*(epsv-INVN*Sg),0.f));

    __builtin_amdgcn_fence(__ATOMIC_RELEASE, "agent");
    __syncthreads();
    if (tid==0) gstoreu((unsigned*)&FLG[b*32+t_own], (unsigned)(k+2));
  }
}

extern "C" void kernel_launch(void* const* d_in, const int* in_sizes, int n_in,
                              void* d_out, int out_size, void* d_ws, size_t ws_size,
                              hipStream_t stream) {
  const float* forecast = (const float*)d_in[0];
  const float* omega    = (const float*)d_in[1];
  const float* omin     = (const float*)d_in[2];
  const float* omax     = (const float*)d_in[3];
  const float* eps      = (const float*)d_in[4];
  const float* pmin     = (const float*)d_in[5];
  const float* pmax     = (const float*)d_in[6];
  const float* bG       = (const float*)d_in[7];
  const float* cG       = (const float*)d_in[8];
  float* out = (float*)d_out;
  float* ws  = (float*)d_ws;
  void* args[] = { &forecast, &omega, &omin, &omax, &eps, &pmin, &pmax, &bG, &cG, &out, &ws };
  hipLaunchCooperativeKernel((const void*)dro_kernel, dim3(NBLK), dim3(NTHR),
                             args, 0, stream);
}

// Round 5
// 1089.019 us; speedup vs baseline: 1.3842x; 1.3842x over previous
//
#include <hip/hip_runtime.h>
#include <hip/hip_cooperative_groups.h>

namespace cg = cooperative_groups;

#define G_ 100
#define T_ 24
#define NSC 128
#define BATCH 8
#define NITER 40
#define NBLK (BATCH*T_)     // 192 WGs: one (batch,t) per WG
#define NTHR 512            // 8 waves -> 2 waves/SIMD for latency hiding
#define GMAX 13

__device__ __forceinline__ float gload(const float* p){
  return __hip_atomic_load(p, __ATOMIC_RELAXED, __HIP_MEMORY_SCOPE_AGENT);
}
__device__ __forceinline__ void gstore(float* p, float v){
  __hip_atomic_store(p, v, __ATOMIC_RELAXED, __HIP_MEMORY_SCOPE_AGENT);
}
__device__ __forceinline__ unsigned gloadu(const unsigned* p){
  return __hip_atomic_load(p, __ATOMIC_RELAXED, __HIP_MEMORY_SCOPE_AGENT);
}
__device__ __forceinline__ void gstoreu(unsigned* p, unsigned v){
  __hip_atomic_store(p, v, __ATOMIC_RELAXED, __HIP_MEMORY_SCOPE_AGENT);
}

// 8-wave block reductions
__device__ __forceinline__ void blockReduce2(float& a, float& b, float* sR){
#pragma unroll
  for (int off=32; off; off>>=1){ a+=__shfl_down(a,off,64); b+=__shfl_down(b,off,64); }
  const int w = threadIdx.x>>6;
  __syncthreads();
  if ((threadIdx.x&63)==0){ sR[w]=a; sR[8+w]=b; }
  __syncthreads();
  a=0.f; b=0.f;
#pragma unroll
  for (int i=0;i<8;++i){ a+=sR[i]; b+=sR[8+i]; }
}
__device__ __forceinline__ void blockReduce3(float& a, float& b, float& c, float* sR){
#pragma unroll
  for (int off=32; off; off>>=1){
    a+=__shfl_down(a,off,64); b+=__shfl_down(b,off,64); c+=__shfl_down(c,off,64);
  }
  const int w = threadIdx.x>>6;
  __syncthreads();
  if ((threadIdx.x&63)==0){ sR[w]=a; sR[8+w]=b; sR[16+w]=c; }
  __syncthreads();
  a=0.f; b=0.f; c=0.f;
#pragma unroll
  for (int i=0;i<8;++i){ a+=sR[i]; b+=sR[8+i]; c+=sR[16+i]; }
}

// wave0 polls the 24 per-slice epoch flags; other waves park at the barrier.
__device__ __forceinline__ void waitEpoch(const unsigned* fl, unsigned tgt, int tid, int lane){
  if (tid < 64){
    for (;;){
      unsigned f = (lane < T_) ? gloadu(&fl[lane]) : tgt;
      if (__ballot(f < tgt) == 0ull) break;
      __builtin_amdgcn_s_sleep(1);
    }
    __builtin_amdgcn_fence(__ATOMIC_ACQUIRE, "agent");
  }
  __syncthreads();
}

// launch_bounds(512,1): 1 WG/CU target -> up to 256 VGPRs/wave, no spills.
// (R4's (512,2) capped at 128 VGPRs -> 23KB/WG/iter scratch spill = 180MB FETCH)
__global__ __launch_bounds__(NTHR, 1) void dro_kernel(
    const float* __restrict__ forecast, const float* __restrict__ omega,
    const float* __restrict__ om_min, const float* __restrict__ om_max,
    const float* __restrict__ eps_in, const float* __restrict__ pmin_g,
    const float* __restrict__ pmax_g, const float* __restrict__ bG,
    const float* __restrict__ cG, float* __restrict__ out, float* __restrict__ ws)
{
  constexpr float LR=2e-4f, VOLL=1000.f, VOSP=50.f, TWO_RHO=20.f, INVN=1.f/128.f;
  const int blk=blockIdx.x;
  const int b=blk&7;
  const int t_own=blk>>3;
  const int tid=threadIdx.x, wave=tid>>6, lane=tid&63;
  const int gcnt  = (wave<4)? 13 : 12;
  const int gbase = (wave<4)? wave*13 : 52+(wave-4)*12;

  __shared__ float sRu[G_], sRd[G_];
  __shared__ float sP[G_], sduM[G_], sddM[G_], sdum[G_], sddm[G_];
  __shared__ float sAccU[G_], sAccD[G_];
  __shared__ float sB[G_], sPmin[G_], sPmax[G_], sC[G_];
  __shared__ float sLS[NSC], sSP[NSC], sOm[NSC];
  __shared__ float sGQ[NSC], sR220[NSC];
  __shared__ float sQn[NSC], sDM[NSC], sDm[NSC], sS2[NSC];
  __shared__ float sQp[NSC*9], sSp[NSC*9];     // [n][wave] stride 9 (conflict-free)
  __shared__ float sQnP[NTHR];
  __shared__ float sRed[24];
  __shared__ float sScal[8];   // 0..2: r3,r4,rP ; 3..6: LSM,SPM,LSm,SPm

  float* QNP = ws;                          // [3][B][24][128]
  float* PP  = ws + 73728;                  // [3][B][24][128] (first 100 used)
  float* QS  = ws + 147456;                 // [3][B][32][2]
  float* GAM = ws + 148992;                 // [3][16]
  float* ST1 = ws + 149040;                 // [B][32]
  unsigned* FLG = (unsigned*)(ws + 149296); // [B][32]

  const float epsv  = eps_in[b];
  const float omaxT = om_max[b*T_ + t_own];
  const float ominT = om_min[b*T_ + t_own];
  const float fctT  = forecast[b*T_ + t_own];
  const unsigned* flB = FLG + b*32;

  // register-resident d_up/d_dn: lane holds n=lane (A) and n=lane+64 (B)
  float duA[GMAX], duB[GMAX], ddA[GMAX], ddB[GMAX];

  // ---------------- init ----------------
  if (tid<G_){
    sB[tid]=bG[tid]; sPmin[tid]=pmin_g[tid]; sPmax[tid]=pmax_g[tid]; sC[tid]=cG[tid];
    sRu[tid]=0.f; sRd[tid]=0.f;
    sduM[tid]=0.f; sddM[tid]=0.f; sdum[tid]=0.f; sddm[tid]=0.f;
  }
  if (tid<NSC){
    const int n=tid;
    sLS[n]=0.f; sSP[n]=0.f; sS2[n]=0.f;
    sOm[n]=omega[(b*NSC+n)*T_+t_own];
    float dM=0.f,dm=0.f;
    for (int t=0;t<T_;++t){
      float o=omega[(b*NSC+n)*T_+t];
      dM+=om_max[b*T_+t]-o; dm+=o-om_min[b*T_+t];
    }
    sDM[n]=dM; sDm[n]=dm;
  }
  if (tid==0){ sScal[3]=0.f; sScal[4]=0.f; sScal[5]=0.f; sScal[6]=0.f; }
  __syncthreads();
#pragma unroll
  for (int j=0;j<GMAX;++j){ duA[j]=0.f; duB[j]=0.f; ddA[j]=0.f; ddB[j]=0.f; }
  {
    float p0=0.f;
    if (tid<G_){
      p0=0.5f*(sPmin[tid]+sPmax[tid]);
      sP[tid]=p0;
      gstore(&PP[b*3072 + t_own*NSC + tid], p0);
    }
    if (tid<NSC) gstore(&QNP[b*3072 + t_own*NSC + tid], 0.f);
    if (tid<2)   gstore(&QS[b*64 + t_own*2 + tid], 0.f);
    if (t_own==0 && tid==0) gstore(&GAM[b], 0.f);
    float rp=p0, dum0=0.f;
    blockReduce2(rp,dum0,sRed);
    if (tid==0){
      sScal[0]=-omaxT; sScal[1]=-ominT; sScal[2]=rp-fctT;
      gstoreu((unsigned*)&FLG[b*32+t_own], 1u);
    }
  }
  __builtin_amdgcn_fence(__ATOMIC_RELEASE, "agent");
  cg::this_grid().sync();

  for (int k=0;k<=NITER;++k){
    waitEpoch(flB, (unsigned)(k+1), tid, lane);

    const int rb = k%3, wb = (k+1)%3;
    const float* qnpR = QNP + rb*24576 + b*3072;
    const float* ppR  = PP  + rb*24576 + b*3072;
    const float* qsR  = QS  + rb*512   + b*64;
    float* qnpW = QNP + wb*24576 + b*3072 + t_own*NSC;
    float* ppW  = PP  + wb*24576 + b*3072 + t_own*NSC;
    float* qsW  = QS  + wb*512   + b*64  + t_own*2;

    const float gamma = gload(&GAM[rb*16 + b]);
    float pm1=0.f, pp1=0.f;
    if (tid<G_){
      if (t_own>0)     pm1 = gload(&ppR[(t_own-1)*NSC + tid]);
      if (t_own<T_-1)  pp1 = gload(&ppR[(t_own+1)*NSC + tid]);
    }
    {
      const int n = tid&127, sb0 = (tid>>7)*6;
      float q=0.f;
#pragma unroll
      for (int s=0;s<6;++s) q += gload(&qnpR[(sb0+s)*NSC + n]);
      sQnP[tid]=q;
    }
    float Qmax = (tid<T_)? gload(&qsR[tid*2])   : 0.f;
    float Qmin = (tid<T_)? gload(&qsR[tid*2+1]) : 0.f;
    blockReduce2(Qmax,Qmin,sRed);      // its syncs also publish sQnP
    if (tid<NSC) sQn[tid]=sQnP[tid]+sQnP[tid+128]+sQnP[tid+256]+sQnP[tid+384];

    if (k==NITER){  // ---------------- final: phi + outputs ----------------
      if (tid<NSC){
        const int n=tid;
        const float m1=Qmax-gamma*sDM[n], m2=Qmin-gamma*sDm[n];
        const float ph=fmaxf(sQn[n],fmaxf(m1,m2));
        sQn[n]=ph;
        if (t_own==0) out[76800 + b*NSC + n]=ph;
      }
      float st=0.f, dum0=0.f;
      if (tid<G_){
        const int g=tid;
        const float Pv=sP[g];
        const float costv=sB[g]*Pv+sC[g];
        st=costv + 0.05f*sB[g]*sRu[g] + 0.02f*sB[g]*sRd[g];
        const int o=b*2400 + g*T_ + t_own;
        out[o]=Pv;
        out[19200+o]=sRu[g];
        out[38400+o]=sRd[g];
        out[57600+o]=costv;
      }
      blockReduce2(st,dum0,sRed);
      if (tid==0) gstore(&ST1[b*32+t_own], st);
      if (t_own==0 && tid==0) out[77824+b]=gamma;
      __builtin_amdgcn_fence(__ATOMIC_RELEASE, "agent");
      __syncthreads();
      if (tid==0) gstoreu((unsigned*)&FLG[b*32+t_own], (unsigned)(NITER+2));
      if (t_own==0){
        waitEpoch(flB, (unsigned)(NITER+2), tid, lane);
        float pm = (tid<NSC)? sQn[tid] : 0.f;
        float s1 = (tid<T_)? gload(&ST1[b*32+tid]) : 0.f;
        blockReduce2(pm,s1,sRed);
        if (tid==0) out[77832+b] = s1 + pm*INVN + epsv*gamma;
      }
      break;
    }

    // ---- weights (balanced_eq ties) + LS/SP update (tid<128) ----
    float g1l=0.f,g2l=0.f,sgl=0.f;
    if (tid<NSC){
      const int n=tid;
      const float Qn=sQn[n];
      const float m1=Qmax-gamma*sDM[n], m2=Qmin-gamma*sDm[n];
      const float inner=fmaxf(m1,m2), ph=fmaxf(Qn,inner);
      const float gQn=(Qn==ph?1.f:0.f)/((inner==ph)?2.f:1.f);
      const float gIn=(inner==ph?1.f:0.f)/((Qn==ph)?2.f:1.f);
      const float gm1=gIn*(m1==inner?1.f:0.f)/((m2==inner)?2.f:1.f);
      const float gm2=gIn*(m2==inner?1.f:0.f)/((m1==inner)?2.f:1.f);
      const float gq=gQn*INVN;
      sGQ[n]=gq;
      g1l=gm1; g2l=gm2; sgl=gm1*sDM[n]+gm2*sDm[n];
      const float r2=sS2[n]+sLS[n]-sSP[n]-sOm[n];
      const float r220=TWO_RHO*r2;
      sR220[n]=r220;
      sLS[n]=fmaxf(sLS[n]-LR*(gq*VOLL+r220),0.f);
      sSP[n]=fmaxf(sSP[n]-LR*(gq*VOSP-r220),0.f);
    }
    float S1s=g1l,S2s=g2l,Sg=sgl;
    blockReduce3(S1s,S2s,Sg,sRed);   // syncs publish sGQ/sR220/new LS,SP

    // ---- pass A: register-resident d update + fused produce partials ----
    const float gqA=sGQ[lane],    r220A=sR220[lane];
    const float gqB=sGQ[lane+64], r220B=sR220[lane+64];
    float qvA=0.f,qvB=0.f,svA=0.f,svB=0.f;
#pragma unroll
    for (int j=0;j<GMAX;++j){
      if (j<gcnt){
        const int g=gbase+j;
        const float bg=sB[g];                 // LDS broadcast (replaces rtuR/rtdR arrays)
        const float rtu=2.f*bg, rtd=0.5f*bg;
        const float ru=sRu[g], rd=sRd[g];     // LDS broadcast reads
        const float r7A=fmaxf(duA[j]-ru,0.f), r8A=fmaxf(ddA[j]-rd,0.f);
        const float r7B=fmaxf(duB[j]-ru,0.f), r8B=fmaxf(ddB[j]-rd,0.f);
        float aU=r7A+r7B, aD=r8A+r8B;
#pragma unroll
        for (int off=32; off; off>>=1){ aU+=__shfl_xor(aU,off,64); aD+=__shfl_xor(aD,off,64); }
        if (lane==0){ sAccU[g]=aU; sAccD[g]=aD; }
        duA[j]=fmaxf(duA[j]-LR*(gqA*rtu+(r220A+TWO_RHO*r7A)),0.f);
        ddA[j]=fmaxf(ddA[j]-LR*(gqA*rtd+(TWO_RHO*r8A-r220A)),0.f);
        duB[j]=fmaxf(duB[j]-LR*(gqB*rtu+(r220B+TWO_RHO*r7B)),0.f);
        ddB[j]=fmaxf(ddB[j]-LR*(gqB*rtd+(TWO_RHO*r8B-r220B)),0.f);
        qvA+=rtu*duA[j]+rtd*ddA[j];  svA+=duA[j]-ddA[j];
        qvB+=rtu*duB[j]+rtd*ddB[j];  svB+=duB[j]-ddB[j];
      }
    }
    sQp[lane*9+wave]=qvA;      sSp[lane*9+wave]=svA;
    sQp[(lane+64)*9+wave]=qvB; sSp[(lane+64)*9+wave]=svB;
    __syncthreads();

    // ---- combine produce partials (waves 4-5) | pass B (tid<100) ----
    if (tid>=256 && tid<384){
      const int n=tid-256;
      float q=0.f,s=0.f;
#pragma unroll
      for (int w=0;w<8;++w){ q+=sQp[n*9+w]; s+=sSp[n*9+w]; }
      sS2[n]=s;
      q += VOLL*sLS[n]+VOSP*sSP[n];
      gstore(&qnpW[n], q);
    }
    const float r3=sScal[0], r4=sScal[1], rP=sScal[2];
    float pQx=0.f,pQn2=0.f,pr3=0.f,pr4=0.f,pP=0.f;
    if (tid<G_){
      const int g=tid;
      const float rupS=sAccU[g], rdnS=sAccD[g];
      const float Pold=sP[g], ru=sRu[g], rd=sRd[g];
      const float duMo=sduM[g], ddMo=sddM[g], dumo=sdum[g], ddmo=sddm[g];
      const float r5 =fmaxf(Pold+ru-sPmax[g],0.f);
      const float r6 =fmaxf(sPmin[g]-Pold+rd,0.f);
      const float r9 =fmaxf(duMo-ru,0.f), r10=fmaxf(ddMo-rd,0.f);
      const float r11=fmaxf(dumo-ru,0.f), r12=fmaxf(ddmo-rd,0.f);
      const float rampg=sPmax[g];
      float gP=sB[g]+TWO_RHO*(rP+r5-r6);
      if (t_own>0){
        const float dp=Pold-pm1;
        gP+=TWO_RHO*fmaxf(fabsf(dp)-rampg,0.f)*(dp>=0.f?1.f:-1.f);
      }
      if (t_own<T_-1){
        const float dq=pp1-Pold;
        gP-=TWO_RHO*fmaxf(fabsf(dq)-rampg,0.f)*(dq>=0.f?1.f:-1.f);
      }
      const float Pn=fminf(fmaxf(Pold-LR*gP,sPmin[g]),sPmax[g]);
      sP[g]=Pn; gstore(&ppW[g],Pn);
      const float rtuB=2.f*sB[g], rtdB=0.5f*sB[g];
      sRu[g]=fmaxf(ru-LR*(0.05f*sB[g]+TWO_RHO*(r5-rupS-r9-r11)),0.f);
      sRd[g]=fmaxf(rd-LR*(0.02f*sB[g]+TWO_RHO*(r6-rdnS-r10-r12)),0.f);
      const float duMn=fmaxf(duMo-LR*(INVN*S1s*rtuB+TWO_RHO*( r3+r9 )),0.f);
      const float ddMn=fmaxf(ddMo-LR*(INVN*S1s*rtdB+TWO_RHO*(-r3+r10)),0.f);
      const float dumn=fmaxf(dumo-LR*(INVN*S2s*rtuB+TWO_RHO*( r4+r11)),0.f);
      const float ddmn=fmaxf(ddmo-LR*(INVN*S2s*rtdB+TWO_RHO*(-r4+r12)),0.f);
      sduM[g]=duMn; sddM[g]=ddMn; sdum[g]=dumn; sddm[g]=ddmn;
      pQx=rtuB*duMn+rtdB*ddMn; pQn2=rtuB*dumn+rtdB*ddmn;
      pr3=duMn-ddMn; pr4=dumn-ddmn; pP=Pn;
    }
    blockReduce3(pQx,pQn2,pr3,sRed);
    blockReduce2(pr4,pP,sRed);
    if (tid==0){
      const float LSMn=fmaxf(sScal[3]-LR*(INVN*S1s*VOLL+TWO_RHO*r3),0.f);
      const float SPMn=fmaxf(sScal[4]-LR*(INVN*S1s*VOSP-TWO_RHO*r3),0.f);
      const float LSmn=fmaxf(sScal[5]-LR*(INVN*S2s*VOLL+TWO_RHO*r4),0.f);
      const float SPmn=fmaxf(sScal[6]-LR*(INVN*S2s*VOSP-TWO_RHO*r4),0.f);
      sScal[3]=LSMn; sScal[4]=SPMn; sScal[5]=LSmn; sScal[6]=SPmn;
      gstore(&qsW[0], pQx + VOLL*LSMn + VOSP*SPMn);
      gstore(&qsW[1], pQn2 + VOLL*LSmn + VOSP*SPmn);
      sScal[0]=pr3 + LSMn - SPMn - omaxT;
      sScal[1]=pr4 + LSmn - SPmn - ominT;
      sScal[2]=pP - fctT;
    }
    if (t_own==0 && tid==448)
      gstore(&GAM[wb*16+b], fmaxf(gamma-LR*(epsv-INVN*Sg),0.f));

    __builtin_amdgcn_fence(__ATOMIC_RELEASE, "agent");
    __syncthreads();
    if (tid==0) gstoreu((unsigned*)&FLG[b*32+t_own], (unsigned)(k+2));
  }
}

extern "C" void kernel_launch(void* const* d_in, const int* in_sizes, int n_in,
                              void* d_out, int out_size, void* d_ws, size_t ws_size,
                              hipStream_t stream) {
  const float* forecast = (const float*)d_in[0];
  const float* omega    = (const float*)d_in[1];
  const float* omin     = (const float*)d_in[2];
  const float* omax     = (const float*)d_in[3];
  const float* eps      = (const float*)d_in[4];
  const float* pmin     = (const float*)d_in[5];
  const float* pmax     = (const float*)d_in[6];
  const float* bG       = (const float*)d_in[7];
  const float* cG       = (const float*)d_in[8];
  float* out = (float*)d_out;
  float* ws  = (float*)d_ws;
  void* args[] = { &forecast, &omega, &omin, &omax, &eps, &pmin, &pmax, &bG, &cG, &out, &ws };
  hipLaunchCooperativeKernel((const void*)dro_kernel, dim3(NBLK), dim3(NTHR),
                             args, 0, stream);
}

// Round 6
// 1046.051 us; speedup vs baseline: 1.4411x; 1.0411x over previous
//
#include <hip/hip_runtime.h>
#include <hip/hip_cooperative_groups.h>

namespace cg = cooperative_groups;

#define G_ 100
#define T_ 24
#define NSC 128
#define BATCH 8
#define NITER 40
#define NBLK (BATCH*T_)     // 192 WGs: one (batch,t) per WG
#define NTHR 512            // 8 waves -> 2 waves/SIMD
#define GMAX 13
#define PAD 32              // 128B line padding for all cross-WG words

__device__ __forceinline__ float gload(const float* p){
  return __hip_atomic_load(p, __ATOMIC_RELAXED, __HIP_MEMORY_SCOPE_AGENT);
}
__device__ __forceinline__ void gstore(float* p, float v){
  __hip_atomic_store(p, v, __ATOMIC_RELAXED, __HIP_MEMORY_SCOPE_AGENT);
}
__device__ __forceinline__ unsigned gloadu(const unsigned* p){
  return __hip_atomic_load(p, __ATOMIC_RELAXED, __HIP_MEMORY_SCOPE_AGENT);
}
__device__ __forceinline__ void gstoreu(unsigned* p, unsigned v){
  __hip_atomic_store(p, v, __ATOMIC_RELAXED, __HIP_MEMORY_SCOPE_AGENT);
}

// 8-wave block reductions
__device__ __forceinline__ void blockReduce2(float& a, float& b, float* sR){
#pragma unroll
  for (int off=32; off; off>>=1){ a+=__shfl_down(a,off,64); b+=__shfl_down(b,off,64); }
  const int w = threadIdx.x>>6;
  __syncthreads();
  if ((threadIdx.x&63)==0){ sR[w]=a; sR[8+w]=b; }
  __syncthreads();
  a=0.f; b=0.f;
#pragma unroll
  for (int i=0;i<8;++i){ a+=sR[i]; b+=sR[8+i]; }
}
__device__ __forceinline__ void blockReduce3(float& a, float& b, float& c, float* sR){
#pragma unroll
  for (int off=32; off; off>>=1){
    a+=__shfl_down(a,off,64); b+=__shfl_down(b,off,64); c+=__shfl_down(c,off,64);
  }
  const int w = threadIdx.x>>6;
  __syncthreads();
  if ((threadIdx.x&63)==0){ sR[w]=a; sR[8+w]=b; sR[16+w]=c; }
  __syncthreads();
  a=0.f; b=0.f; c=0.f;
#pragma unroll
  for (int i=0;i<8;++i){ a+=sR[i]; b+=sR[8+i]; c+=sR[16+i]; }
}

// wave0 polls the 24 per-slice epoch flags (each on its OWN cache line).
__device__ __forceinline__ void waitEpoch(const unsigned* flB, unsigned tgt, int tid, int lane){
  if (tid < 64){
    for (;;){
      unsigned f = (lane < T_) ? gloadu(&flB[lane*PAD]) : tgt;
      if (__ballot(f < tgt) == 0ull) break;
      __builtin_amdgcn_s_sleep(2);
    }
    __builtin_amdgcn_fence(__ATOMIC_ACQUIRE, "agent");
  }
  __syncthreads();
}

__global__ __launch_bounds__(NTHR, 1) void dro_kernel(
    const float* __restrict__ forecast, const float* __restrict__ omega,
    const float* __restrict__ om_min, const float* __restrict__ om_max,
    const float* __restrict__ eps_in, const float* __restrict__ pmin_g,
    const float* __restrict__ pmax_g, const float* __restrict__ bG,
    const float* __restrict__ cG, float* __restrict__ out, float* __restrict__ ws)
{
  constexpr float LR=2e-4f, VOLL=1000.f, VOSP=50.f, TWO_RHO=20.f, INVN=1.f/128.f;
  const int blk=blockIdx.x;
  const int b=blk&7;
  const int t_own=blk>>3;
  const int tid=threadIdx.x, wave=tid>>6, lane=tid&63;
  const int gcnt  = (wave<4)? 13 : 12;
  const int gbase = (wave<4)? wave*13 : 52+(wave-4)*12;

  __shared__ float sRu[G_], sRd[G_];
  __shared__ float sP[G_], sduM[G_], sddM[G_], sdum[G_], sddm[G_];
  __shared__ float sAccU[G_], sAccD[G_];
  __shared__ float sB[G_], sPmin[G_], sPmax[G_], sC[G_];
  __shared__ float sLS[NSC], sSP[NSC], sOm[NSC];
  __shared__ float sGQ[NSC], sR220[NSC];
  __shared__ float sQn[NSC], sDM[NSC], sDm[NSC], sS2[NSC];
  __shared__ float sQp[NSC*9], sSp[NSC*9];     // [n][wave] stride 9 (conflict-free)
  __shared__ float sQnP[NTHR];
  __shared__ float sRed[24];
  __shared__ float sScal[8];   // 0..2: r3,r4,rP ; 3..6: LSM,SPM,LSm,SPm

  // ---- ws layout (floats). All cross-WG scalars padded to 128B lines. ----
  float* QNP = ws;                          // [3][B][24][128]
  float* PP  = ws + 73728;                  // [3][B][24][128] (first 100 used)
  float* QS  = ws + 147456;                 // [3][B][24][PAD]  (Qmax@0, Qmin@1)
  float* GAM = ws + 165888;                 // [3][B][PAD]
  float* ST1 = ws + 166656;                 // [B][24][PAD]
  unsigned* FLG = (unsigned*)(ws + 172800); // [B][24][PAD]

  const float epsv  = eps_in[b];
  const float omaxT = om_max[b*T_ + t_own];
  const float ominT = om_min[b*T_ + t_own];
  const float fctT  = forecast[b*T_ + t_own];
  const unsigned* flB = FLG + b*T_*PAD;
  unsigned* myFlag    = FLG + (b*T_ + t_own)*PAD;

  // register-resident d_up/d_dn: lane holds n=lane (A) and n=lane+64 (B)
  float duA[GMAX], duB[GMAX], ddA[GMAX], ddB[GMAX];

  // ---------------- init ----------------
  if (tid<G_){
    sB[tid]=bG[tid]; sPmin[tid]=pmin_g[tid]; sPmax[tid]=pmax_g[tid]; sC[tid]=cG[tid];
    sRu[tid]=0.f; sRd[tid]=0.f;
    sduM[tid]=0.f; sddM[tid]=0.f; sdum[tid]=0.f; sddm[tid]=0.f;
  }
  if (tid<NSC){
    const int n=tid;
    sLS[n]=0.f; sSP[n]=0.f; sS2[n]=0.f;
    sOm[n]=omega[(b*NSC+n)*T_+t_own];
    float dM=0.f,dm=0.f;
    for (int t=0;t<T_;++t){
      float o=omega[(b*NSC+n)*T_+t];
      dM+=om_max[b*T_+t]-o; dm+=o-om_min[b*T_+t];
    }
    sDM[n]=dM; sDm[n]=dm;
  }
  if (tid==0){ sScal[3]=0.f; sScal[4]=0.f; sScal[5]=0.f; sScal[6]=0.f; }
  __syncthreads();
#pragma unroll
  for (int j=0;j<GMAX;++j){ duA[j]=0.f; duB[j]=0.f; ddA[j]=0.f; ddB[j]=0.f; }
  {
    float p0=0.f;
    if (tid<G_){
      p0=0.5f*(sPmin[tid]+sPmax[tid]);
      sP[tid]=p0;
      gstore(&PP[b*3072 + t_own*NSC + tid], p0);
    }
    if (tid<NSC) gstore(&QNP[b*3072 + t_own*NSC + tid], 0.f);
    if (tid<2)   gstore(&QS[(b*T_ + t_own)*PAD + tid], 0.f);
    if (t_own==0 && tid==0) gstore(&GAM[b*PAD], 0.f);
    float rp=p0, dum0=0.f;
    blockReduce2(rp,dum0,sRed);
    if (tid==0){
      sScal[0]=-omaxT; sScal[1]=-ominT; sScal[2]=rp-fctT;
      gstoreu(myFlag, 1u);
    }
  }
  __builtin_amdgcn_fence(__ATOMIC_RELEASE, "agent");
  cg::this_grid().sync();

  for (int k=0;k<=NITER;++k){
    waitEpoch(flB, (unsigned)(k+1), tid, lane);

    const int rb = k%3, wb = (k+1)%3;
    const float* qnpR = QNP + rb*24576 + b*3072;
    const float* ppR  = PP  + rb*24576 + b*3072;
    const float* qsR  = QS  + (rb*BATCH + b)*T_*PAD;
    float* qnpW = QNP + wb*24576 + b*3072 + t_own*NSC;
    float* ppW  = PP  + wb*24576 + b*3072 + t_own*NSC;
    float* qsW  = QS  + (wb*BATCH + b)*T_*PAD + t_own*PAD;

    const float gamma = gload(&GAM[(rb*BATCH + b)*PAD]);
    float pm1=0.f, pp1=0.f;
    if (tid<G_){
      if (t_own>0)     pm1 = gload(&ppR[(t_own-1)*NSC + tid]);
      if (t_own<T_-1)  pp1 = gload(&ppR[(t_own+1)*NSC + tid]);
    }
    {
      const int n = tid&127, sb0 = (tid>>7)*6;
      float q=0.f;
#pragma unroll
      for (int s=0;s<6;++s) q += gload(&qnpR[(sb0+s)*NSC + n]);
      sQnP[tid]=q;
    }
    float Qmax = (tid<T_)? gload(&qsR[tid*PAD])   : 0.f;
    float Qmin = (tid<T_)? gload(&qsR[tid*PAD+1]) : 0.f;
    blockReduce2(Qmax,Qmin,sRed);      // its syncs also publish sQnP
    if (tid<NSC) sQn[tid]=sQnP[tid]+sQnP[tid+128]+sQnP[tid+256]+sQnP[tid+384];

    if (k==NITER){  // ---------------- final: phi + outputs ----------------
      if (tid<NSC){
        const int n=tid;
        const float m1=Qmax-gamma*sDM[n], m2=Qmin-gamma*sDm[n];
        const float ph=fmaxf(sQn[n],fmaxf(m1,m2));
        sQn[n]=ph;
        if (t_own==0) out[76800 + b*NSC + n]=ph;
      }
      float st=0.f, dum0=0.f;
      if (tid<G_){
        const int g=tid;
        const float Pv=sP[g];
        const float costv=sB[g]*Pv+sC[g];
        st=costv + 0.05f*sB[g]*sRu[g] + 0.02f*sB[g]*sRd[g];
        const int o=b*2400 + g*T_ + t_own;
        out[o]=Pv;
        out[19200+o]=sRu[g];
        out[38400+o]=sRd[g];
        out[57600+o]=costv;
      }
      blockReduce2(st,dum0,sRed);
      if (tid==0) gstore(&ST1[(b*T_+t_own)*PAD], st);
      if (t_own==0 && tid==0) out[77824+b]=gamma;
      __builtin_amdgcn_fence(__ATOMIC_RELEASE, "agent");
      __syncthreads();
      if (tid==0) gstoreu(myFlag, (unsigned)(NITER+2));
      if (t_own==0){
        waitEpoch(flB, (unsigned)(NITER+2), tid, lane);
        float pm = (tid<NSC)? sQn[tid] : 0.f;
        float s1 = (tid<T_)? gload(&ST1[(b*T_+tid)*PAD]) : 0.f;
        blockReduce2(pm,s1,sRed);
        if (tid==0) out[77832+b] = s1 + pm*INVN + epsv*gamma;
      }
      break;
    }

    // ---- weights (balanced_eq ties) + LS/SP update (tid<128) ----
    float g1l=0.f,g2l=0.f,sgl=0.f;
    if (tid<NSC){
      const int n=tid;
      const float Qn=sQn[n];
      const float m1=Qmax-gamma*sDM[n], m2=Qmin-gamma*sDm[n];
      const float inner=fmaxf(m1,m2), ph=fmaxf(Qn,inner);
      const float gQn=(Qn==ph?1.f:0.f)/((inner==ph)?2.f:1.f);
      const float gIn=(inner==ph?1.f:0.f)/((Qn==ph)?2.f:1.f);
      const float gm1=gIn*(m1==inner?1.f:0.f)/((m2==inner)?2.f:1.f);
      const float gm2=gIn*(m2==inner?1.f:0.f)/((m1==inner)?2.f:1.f);
      const float gq=gQn*INVN;
      sGQ[n]=gq;
      g1l=gm1; g2l=gm2; sgl=gm1*sDM[n]+gm2*sDm[n];
      const float r2=sS2[n]+sLS[n]-sSP[n]-sOm[n];
      const float r220=TWO_RHO*r2;
      sR220[n]=r220;
      sLS[n]=fmaxf(sLS[n]-LR*(gq*VOLL+r220),0.f);
      sSP[n]=fmaxf(sSP[n]-LR*(gq*VOSP-r220),0.f);
    }
    float S1s=g1l,S2s=g2l,Sg=sgl;
    blockReduce3(S1s,S2s,Sg,sRed);   // syncs publish sGQ/sR220/new LS,SP

    // ---- pass A: register-resident d update + fused produce partials ----
    const float gqA=sGQ[lane],    r220A=sR220[lane];
    const float gqB=sGQ[lane+64], r220B=sR220[lane+64];
    float qvA=0.f,qvB=0.f,svA=0.f,svB=0.f;
#pragma unroll
    for (int j=0;j<GMAX;++j){
      if (j<gcnt){
        const int g=gbase+j;
        const float bg=sB[g];
        const float rtu=2.f*bg, rtd=0.5f*bg;
        const float ru=sRu[g], rd=sRd[g];
        const float r7A=fmaxf(duA[j]-ru,0.f), r8A=fmaxf(ddA[j]-rd,0.f);
        const float r7B=fmaxf(duB[j]-ru,0.f), r8B=fmaxf(ddB[j]-rd,0.f);
        float aU=r7A+r7B, aD=r8A+r8B;
#pragma unroll
        for (int off=32; off; off>>=1){ aU+=__shfl_xor(aU,off,64); aD+=__shfl_xor(aD,off,64); }
        if (lane==0){ sAccU[g]=aU; sAccD[g]=aD; }
        duA[j]=fmaxf(duA[j]-LR*(gqA*rtu+(r220A+TWO_RHO*r7A)),0.f);
        ddA[j]=fmaxf(ddA[j]-LR*(gqA*rtd+(TWO_RHO*r8A-r220A)),0.f);
        duB[j]=fmaxf(duB[j]-LR*(gqB*rtu+(r220B+TWO_RHO*r7B)),0.f);
        ddB[j]=fmaxf(ddB[j]-LR*(gqB*rtd+(TWO_RHO*r8B-r220B)),0.f);
        qvA+=rtu*duA[j]+rtd*ddA[j];  svA+=duA[j]-ddA[j];
        qvB+=rtu*duB[j]+rtd*ddB[j];  svB+=duB[j]-ddB[j];
      }
    }
    sQp[lane*9+wave]=qvA;      sSp[lane*9+wave]=svA;
    sQp[(lane+64)*9+wave]=qvB; sSp[(lane+64)*9+wave]=svB;
    __syncthreads();

    // ---- combine produce partials (waves 4-5) | pass B (tid<100) ----
    if (tid>=256 && tid<384){
      const int n=tid-256;
      float q=0.f,s=0.f;
#pragma unroll
      for (int w=0;w<8;++w){ q+=sQp[n*9+w]; s+=sSp[n*9+w]; }
      sS2[n]=s;
      q += VOLL*sLS[n]+VOSP*sSP[n];
      gstore(&qnpW[n], q);
    }
    const float r3=sScal[0], r4=sScal[1], rP=sScal[2];
    float pQx=0.f,pQn2=0.f,pr3=0.f,pr4=0.f,pP=0.f;
    if (tid<G_){
      const int g=tid;
      const float rupS=sAccU[g], rdnS=sAccD[g];
      const float Pold=sP[g], ru=sRu[g], rd=sRd[g];
      const float duMo=sduM[g], ddMo=sddM[g], dumo=sdum[g], ddmo=sddm[g];
      const float r5 =fmaxf(Pold+ru-sPmax[g],0.f);
      const float r6 =fmaxf(sPmin[g]-Pold+rd,0.f);
      const float r9 =fmaxf(duMo-ru,0.f), r10=fmaxf(ddMo-rd,0.f);
      const float r11=fmaxf(dumo-ru,0.f), r12=fmaxf(ddmo-rd,0.f);
      const float rampg=sPmax[g];
      float gP=sB[g]+TWO_RHO*(rP+r5-r6);
      if (t_own>0){
        const float dp=Pold-pm1;
        gP+=TWO_RHO*fmaxf(fabsf(dp)-rampg,0.f)*(dp>=0.f?1.f:-1.f);
      }
      if (t_own<T_-1){
        const float dq=pp1-Pold;
        gP-=TWO_RHO*fmaxf(fabsf(dq)-rampg,0.f)*(dq>=0.f?1.f:-1.f);
      }
      const float Pn=fminf(fmaxf(Pold-LR*gP,sPmin[g]),sPmax[g]);
      sP[g]=Pn; gstore(&ppW[g],Pn);
      const float rtuB=2.f*sB[g], rtdB=0.5f*sB[g];
      sRu[g]=fmaxf(ru-LR*(0.05f*sB[g]+TWO_RHO*(r5-rupS-r9-r11)),0.f);
      sRd[g]=fmaxf(rd-LR*(0.02f*sB[g]+TWO_RHO*(r6-rdnS-r10-r12)),0.f);
      const float duMn=fmaxf(duMo-LR*(INVN*S1s*rtuB+TWO_RHO*( r3+r9 )),0.f);
      const float ddMn=fmaxf(ddMo-LR*(INVN*S1s*rtdB+TWO_RHO*(-r3+r10)),0.f);
      const float dumn=fmaxf(dumo-LR*(INVN*S2s*rtuB+TWO_RHO*( r4+r11)),0.f);
      const float ddmn=fmaxf(ddmo-LR*(INVN*S2s*rtdB+TWO_RHO*(-r4+r12)),0.f);
      sduM[g]=duMn; sddM[g]=ddMn; sdum[g]=dumn; sddm[g]=ddmn;
      pQx=rtuB*duMn+rtdB*ddMn; pQn2=rtuB*dumn+rtdB*ddmn;
      pr3=duMn-ddMn; pr4=dumn-ddmn; pP=Pn;
    }
    blockReduce3(pQx,pQn2,pr3,sRed);
    blockReduce2(pr4,pP,sRed);
    if (tid==0){
      const float LSMn=fmaxf(sScal[3]-LR*(INVN*S1s*VOLL+TWO_RHO*r3),0.f);
      const float SPMn=fmaxf(sScal[4]-LR*(INVN*S1s*VOSP-TWO_RHO*r3),0.f);
      const float LSmn=fmaxf(sScal[5]-LR*(INVN*S2s*VOLL+TWO_RHO*r4),0.f);
      const float SPmn=fmaxf(sScal[6]-LR*(INVN*S2s*VOSP-TWO_RHO*r4),0.f);
      sScal[3]=LSMn; sScal[4]=SPMn; sScal[5]=LSmn; sScal[6]=SPmn;
      gstore(&qsW[0], pQx + VOLL*LSMn + VOSP*SPMn);
      gstore(&qsW[1], pQn2 + VOLL*LSmn + VOSP*SPmn);
      sScal[0]=pr3 + LSMn - SPMn - omaxT;
      sScal[1]=pr4 + LSmn - SPmn - ominT;
      sScal[2]=pP - fctT;
    }
    if (t_own==0 && tid==448)
      gstore(&GAM[(wb*BATCH+b)*PAD], fmaxf(gamma-LR*(epsv-INVN*Sg),0.f));

    __builtin_amdgcn_fence(__ATOMIC_RELEASE, "agent");
    __syncthreads();
    if (tid==0) gstoreu(myFlag, (unsigned)(k+2));
  }
}

extern "C" void kernel_launch(void* const* d_in, const int* in_sizes, int n_in,
                              void* d_out, int out_size, void* d_ws, size_t ws_size,
                              hipStream_t stream) {
  const float* forecast = (const float*)d_in[0];
  const float* omega    = (const float*)d_in[1];
  const float* omin     = (const float*)d_in[2];
  const float* omax     = (const float*)d_in[3];
  const float* eps      = (const float*)d_in[4];
  const float* pmin     = (const float*)d_in[5];
  const float* pmax     = (const float*)d_in[6];
  const float* bG       = (const float*)d_in[7];
  const float* cG       = (const float*)d_in[8];
  float* out = (float*)d_out;
  float* ws  = (float*)d_ws;
  void* args[] = { &forecast, &omega, &omin, &omax, &eps, &pmin, &pmax, &bG, &cG, &out, &ws };
  hipLaunchCooperativeKernel((const void*)dro_kernel, dim3(NBLK), dim3(NTHR),
                             args, 0, stream);
}

// Round 7
// 557.342 us; speedup vs baseline: 2.7047x; 1.8769x over previous
//
#include <hip/hip_runtime.h>
#include <hip/hip_cooperative_groups.h>

namespace cg = cooperative_groups;

#define G_ 100
#define T_ 24
#define NSC 128
#define BATCH 8
#define NITER 40
#define NBLK (BATCH*T_)     // 192 WGs: one (batch,t) per WG
#define NTHR 512            // 8 waves -> 2 waves/SIMD
#define GMAX 13
#define PAD 32              // 128B line padding for all cross-WG words

// Relaxed agent-scope atomics: on gfx950 these emit sc1-flagged global ops
// that are LLC-direct (per-XCD L2 is not agent-coherent, so the compiler
// must bypass it). All cross-WG data uses these => no cache-maintenance
// fences needed; ordering is done with s_waitcnt vmcnt(0) + barrier.
__device__ __forceinline__ float gload(const float* p){
  return __hip_atomic_load(p, __ATOMIC_RELAXED, __HIP_MEMORY_SCOPE_AGENT);
}
__device__ __forceinline__ void gstore(float* p, float v){
  __hip_atomic_store(p, v, __ATOMIC_RELAXED, __HIP_MEMORY_SCOPE_AGENT);
}
__device__ __forceinline__ unsigned gloadu(const unsigned* p){
  return __hip_atomic_load(p, __ATOMIC_RELAXED, __HIP_MEMORY_SCOPE_AGENT);
}
__device__ __forceinline__ void gstoreu(unsigned* p, unsigned v){
  __hip_atomic_store(p, v, __ATOMIC_RELAXED, __HIP_MEMORY_SCOPE_AGENT);
}

// 8-wave block reductions
__device__ __forceinline__ void blockReduce2(float& a, float& b, float* sR){
#pragma unroll
  for (int off=32; off; off>>=1){ a+=__shfl_down(a,off,64); b+=__shfl_down(b,off,64); }
  const int w = threadIdx.x>>6;
  __syncthreads();
  if ((threadIdx.x&63)==0){ sR[w]=a; sR[8+w]=b; }
  __syncthreads();
  a=0.f; b=0.f;
#pragma unroll
  for (int i=0;i<8;++i){ a+=sR[i]; b+=sR[8+i]; }
}
__device__ __forceinline__ void blockReduce3(float& a, float& b, float& c, float* sR){
#pragma unroll
  for (int off=32; off; off>>=1){
    a+=__shfl_down(a,off,64); b+=__shfl_down(b,off,64); c+=__shfl_down(c,off,64);
  }
  const int w = threadIdx.x>>6;
  __syncthreads();
  if ((threadIdx.x&63)==0){ sR[w]=a; sR[8+w]=b; sR[16+w]=c; }
  __syncthreads();
  a=0.f; b=0.f; c=0.f;
#pragma unroll
  for (int i=0;i<8;++i){ a+=sR[i]; b+=sR[8+i]; c+=sR[16+i]; }
}

// wave0 polls the 24 per-slice epoch flags (each on its own line).
// NO acquire fence: data loads after the barrier are sc1 (LLC-direct) and
// control-dependent on the observed flag value.
__device__ __forceinline__ void waitEpoch(const unsigned* flB, unsigned tgt, int tid, int lane){
  if (tid < 64){
    for (;;){
      unsigned f = (lane < T_) ? gloadu(&flB[lane*PAD]) : tgt;
      if (__ballot(f < tgt) == 0ull) break;
      __builtin_amdgcn_s_sleep(1);
    }
  }
  __syncthreads();
}

__global__ __launch_bounds__(NTHR, 1) void dro_kernel(
    const float* __restrict__ forecast, const float* __restrict__ omega,
    const float* __restrict__ om_min, const float* __restrict__ om_max,
    const float* __restrict__ eps_in, const float* __restrict__ pmin_g,
    const float* __restrict__ pmax_g, const float* __restrict__ bG,
    const float* __restrict__ cG, float* __restrict__ out, float* __restrict__ ws)
{
  constexpr float LR=2e-4f, VOLL=1000.f, VOSP=50.f, TWO_RHO=20.f, INVN=1.f/128.f;
  const int blk=blockIdx.x;
  const int b=blk&7;
  const int t_own=blk>>3;
  const int tid=threadIdx.x, wave=tid>>6, lane=tid&63;
  const int gcnt  = (wave<4)? 13 : 12;
  const int gbase = (wave<4)? wave*13 : 52+(wave-4)*12;

  __shared__ float sRu[G_], sRd[G_];
  __shared__ float sP[G_], sduM[G_], sddM[G_], sdum[G_], sddm[G_];
  __shared__ float sAccU[G_], sAccD[G_];
  __shared__ float sB[G_], sPmin[G_], sPmax[G_], sC[G_];
  __shared__ float sLS[NSC], sSP[NSC], sOm[NSC];
  __shared__ float sGQ[NSC], sR220[NSC];
  __shared__ float sQn[NSC], sDM[NSC], sDm[NSC], sS2[NSC];
  __shared__ float sQp[NSC*9], sSp[NSC*9];     // [n][wave] stride 9 (conflict-free)
  __shared__ float sQnP[NTHR];
  __shared__ float sRed[24];
  __shared__ float sScal[8];   // 0..2: r3,r4,rP ; 3..6: LSM,SPM,LSm,SPm

  // ---- ws layout (floats). Cross-WG scalars padded to 128B lines. ----
  float* QNP = ws;                          // [3][B][24][128]
  float* PP  = ws + 73728;                  // [3][B][24][128] (first 100 used)
  float* QS  = ws + 147456;                 // [3][B][24][PAD]  (Qmax@0, Qmin@1)
  float* GAM = ws + 165888;                 // [3][B][PAD]
  float* ST1 = ws + 166656;                 // [B][24][PAD]
  unsigned* FLG = (unsigned*)(ws + 172800); // [B][24][PAD]

  const float epsv  = eps_in[b];
  const float omaxT = om_max[b*T_ + t_own];
  const float ominT = om_min[b*T_ + t_own];
  const float fctT  = forecast[b*T_ + t_own];
  const unsigned* flB = FLG + b*T_*PAD;
  unsigned* myFlag    = FLG + (b*T_ + t_own)*PAD;

  // register-resident d_up/d_dn: lane holds n=lane (A) and n=lane+64 (B)
  float duA[GMAX], duB[GMAX], ddA[GMAX], ddB[GMAX];

  // ---------------- init ----------------
  if (tid<G_){
    sB[tid]=bG[tid]; sPmin[tid]=pmin_g[tid]; sPmax[tid]=pmax_g[tid]; sC[tid]=cG[tid];
    sRu[tid]=0.f; sRd[tid]=0.f;
    sduM[tid]=0.f; sddM[tid]=0.f; sdum[tid]=0.f; sddm[tid]=0.f;
  }
  if (tid<NSC){
    const int n=tid;
    sLS[n]=0.f; sSP[n]=0.f; sS2[n]=0.f;
    sOm[n]=omega[(b*NSC+n)*T_+t_own];
    float dM=0.f,dm=0.f;
    for (int t=0;t<T_;++t){
      float o=omega[(b*NSC+n)*T_+t];
      dM+=om_max[b*T_+t]-o; dm+=o-om_min[b*T_+t];
    }
    sDM[n]=dM; sDm[n]=dm;
  }
  if (tid==0){ sScal[3]=0.f; sScal[4]=0.f; sScal[5]=0.f; sScal[6]=0.f; }
  __syncthreads();
#pragma unroll
  for (int j=0;j<GMAX;++j){ duA[j]=0.f; duB[j]=0.f; ddA[j]=0.f; ddB[j]=0.f; }
  {
    float p0=0.f;
    if (tid<G_){
      p0=0.5f*(sPmin[tid]+sPmax[tid]);
      sP[tid]=p0;
      gstore(&PP[b*3072 + t_own*NSC + tid], p0);
    }
    if (tid<NSC) gstore(&QNP[b*3072 + t_own*NSC + tid], 0.f);
    if (tid<2)   gstore(&QS[(b*T_ + t_own)*PAD + tid], 0.f);
    if (t_own==0 && tid==0) gstore(&GAM[b*PAD], 0.f);
    float rp=p0, dum0=0.f;
    blockReduce2(rp,dum0,sRed);
    if (tid==0){
      sScal[0]=-omaxT; sScal[1]=-ominT; sScal[2]=rp-fctT;
      gstoreu(myFlag, 1u);
    }
  }
  __builtin_amdgcn_s_waitcnt(0);
  cg::this_grid().sync();   // one-time; its internal fence is fine here

  for (int k=0;k<=NITER;++k){
    waitEpoch(flB, (unsigned)(k+1), tid, lane);

    const int rb = k%3, wb = (k+1)%3;
    const float* qnpR = QNP + rb*24576 + b*3072;
    const float* ppR  = PP  + rb*24576 + b*3072;
    const float* qsR  = QS  + (rb*BATCH + b)*T_*PAD;
    float* qnpW = QNP + wb*24576 + b*3072 + t_own*NSC;
    float* ppW  = PP  + wb*24576 + b*3072 + t_own*NSC;
    float* qsW  = QS  + (wb*BATCH + b)*T_*PAD + t_own*PAD;

    const float gamma = gload(&GAM[(rb*BATCH + b)*PAD]);
    float pm1=0.f, pp1=0.f;
    if (tid<G_){
      if (t_own>0)     pm1 = gload(&ppR[(t_own-1)*NSC + tid]);
      if (t_own<T_-1)  pp1 = gload(&ppR[(t_own+1)*NSC + tid]);
    }
    {
      const int n = tid&127, sb0 = (tid>>7)*6;
      float q=0.f;
#pragma unroll
      for (int s=0;s<6;++s) q += gload(&qnpR[(sb0+s)*NSC + n]);
      sQnP[tid]=q;
    }
    float Qmax = (tid<T_)? gload(&qsR[tid*PAD])   : 0.f;
    float Qmin = (tid<T_)? gload(&qsR[tid*PAD+1]) : 0.f;
    blockReduce2(Qmax,Qmin,sRed);      // its syncs also publish sQnP
    if (tid<NSC) sQn[tid]=sQnP[tid]+sQnP[tid+128]+sQnP[tid+256]+sQnP[tid+384];

    if (k==NITER){  // ---------------- final: phi + outputs ----------------
      if (tid<NSC){
        const int n=tid;
        const float m1=Qmax-gamma*sDM[n], m2=Qmin-gamma*sDm[n];
        const float ph=fmaxf(sQn[n],fmaxf(m1,m2));
        sQn[n]=ph;
        if (t_own==0) out[76800 + b*NSC + n]=ph;
      }
      float st=0.f, dum0=0.f;
      if (tid<G_){
        const int g=tid;
        const float Pv=sP[g];
        const float costv=sB[g]*Pv+sC[g];
        st=costv + 0.05f*sB[g]*sRu[g] + 0.02f*sB[g]*sRd[g];
        const int o=b*2400 + g*T_ + t_own;
        out[o]=Pv;
        out[19200+o]=sRu[g];
        out[38400+o]=sRd[g];
        out[57600+o]=costv;
      }
      blockReduce2(st,dum0,sRed);
      if (tid==0) gstore(&ST1[(b*T_+t_own)*PAD], st);
      if (t_own==0 && tid==0) out[77824+b]=gamma;
      __builtin_amdgcn_s_waitcnt(0);
      __syncthreads();
      if (tid==0) gstoreu(myFlag, (unsigned)(NITER+2));
      if (t_own==0){
        waitEpoch(flB, (unsigned)(NITER+2), tid, lane);
        float pm = (tid<NSC)? sQn[tid] : 0.f;
        float s1 = (tid<T_)? gload(&ST1[(b*T_+tid)*PAD]) : 0.f;
        blockReduce2(pm,s1,sRed);
        if (tid==0) out[77832+b] = s1 + pm*INVN + epsv*gamma;
      }
      break;
    }

    // ---- weights (balanced_eq ties) + LS/SP update (tid<128) ----
    float g1l=0.f,g2l=0.f,sgl=0.f;
    if (tid<NSC){
      const int n=tid;
      const float Qn=sQn[n];
      const float m1=Qmax-gamma*sDM[n], m2=Qmin-gamma*sDm[n];
      const float inner=fmaxf(m1,m2), ph=fmaxf(Qn,inner);
      const float gQn=(Qn==ph?1.f:0.f)/((inner==ph)?2.f:1.f);
      const float gIn=(inner==ph?1.f:0.f)/((Qn==ph)?2.f:1.f);
      const float gm1=gIn*(m1==inner?1.f:0.f)/((m2==inner)?2.f:1.f);
      const float gm2=gIn*(m2==inner?1.f:0.f)/((m1==inner)?2.f:1.f);
      const float gq=gQn*INVN;
      sGQ[n]=gq;
      g1l=gm1; g2l=gm2; sgl=gm1*sDM[n]+gm2*sDm[n];
      const float r2=sS2[n]+sLS[n]-sSP[n]-sOm[n];
      const float r220=TWO_RHO*r2;
      sR220[n]=r220;
      sLS[n]=fmaxf(sLS[n]-LR*(gq*VOLL+r220),0.f);
      sSP[n]=fmaxf(sSP[n]-LR*(gq*VOSP-r220),0.f);
    }
    float S1s=g1l,S2s=g2l,Sg=sgl;
    blockReduce3(S1s,S2s,Sg,sRed);   // syncs publish sGQ/sR220/new LS,SP

    // ---- pass A: register-resident d update + fused produce partials ----
    const float gqA=sGQ[lane],    r220A=sR220[lane];
    const float gqB=sGQ[lane+64], r220B=sR220[lane+64];
    float qvA=0.f,qvB=0.f,svA=0.f,svB=0.f;
#pragma unroll
    for (int j=0;j<GMAX;++j){
      if (j<gcnt){
        const int g=gbase+j;
        const float bg=sB[g];
        const float rtu=2.f*bg, rtd=0.5f*bg;
        const float ru=sRu[g], rd=sRd[g];
        const float r7A=fmaxf(duA[j]-ru,0.f), r8A=fmaxf(ddA[j]-rd,0.f);
        const float r7B=fmaxf(duB[j]-ru,0.f), r8B=fmaxf(ddB[j]-rd,0.f);
        float aU=r7A+r7B, aD=r8A+r8B;
#pragma unroll
        for (int off=32; off; off>>=1){ aU+=__shfl_xor(aU,off,64); aD+=__shfl_xor(aD,off,64); }
        if (lane==0){ sAccU[g]=aU; sAccD[g]=aD; }
        duA[j]=fmaxf(duA[j]-LR*(gqA*rtu+(r220A+TWO_RHO*r7A)),0.f);
        ddA[j]=fmaxf(ddA[j]-LR*(gqA*rtd+(TWO_RHO*r8A-r220A)),0.f);
        duB[j]=fmaxf(duB[j]-LR*(gqB*rtu+(r220B+TWO_RHO*r7B)),0.f);
        ddB[j]=fmaxf(ddB[j]-LR*(gqB*rtd+(TWO_RHO*r8B-r220B)),0.f);
        qvA+=rtu*duA[j]+rtd*ddA[j];  svA+=duA[j]-ddA[j];
        qvB+=rtu*duB[j]+rtd*ddB[j];  svB+=duB[j]-ddB[j];
      }
    }
    sQp[lane*9+wave]=qvA;      sSp[lane*9+wave]=svA;
    sQp[(lane+64)*9+wave]=qvB; sSp[(lane+64)*9+wave]=svB;
    __syncthreads();

    // ---- combine produce partials (waves 4-5) | pass B (tid<100) ----
    if (tid>=256 && tid<384){
      const int n=tid-256;
      float q=0.f,s=0.f;
#pragma unroll
      for (int w=0;w<8;++w){ q+=sQp[n*9+w]; s+=sSp[n*9+w]; }
      sS2[n]=s;
      q += VOLL*sLS[n]+VOSP*sSP[n];
      gstore(&qnpW[n], q);
    }
    const float r3=sScal[0], r4=sScal[1], rP=sScal[2];
    float pQx=0.f,pQn2=0.f,pr3=0.f,pr4=0.f,pP=0.f;
    if (tid<G_){
      const int g=tid;
      const float rupS=sAccU[g], rdnS=sAccD[g];
      const float Pold=sP[g], ru=sRu[g], rd=sRd[g];
      const float duMo=sduM[g], ddMo=sddM[g], dumo=sdum[g], ddmo=sddm[g];
      const float r5 =fmaxf(Pold+ru-sPmax[g],0.f);
      const float r6 =fmaxf(sPmin[g]-Pold+rd,0.f);
      const float r9 =fmaxf(duMo-ru,0.f), r10=fmaxf(ddMo-rd,0.f);
      const float r11=fmaxf(dumo-ru,0.f), r12=fmaxf(ddmo-rd,0.f);
      const float rampg=sPmax[g];
      float gP=sB[g]+TWO_RHO*(rP+r5-r6);
      if (t_own>0){
        const float dp=Pold-pm1;
        gP+=TWO_RHO*fmaxf(fabsf(dp)-rampg,0.f)*(dp>=0.f?1.f:-1.f);
      }
      if (t_own<T_-1){
        const float dq=pp1-Pold;
        gP-=TWO_RHO*fmaxf(fabsf(dq)-rampg,0.f)*(dq>=0.f?1.f:-1.f);
      }
      const float Pn=fminf(fmaxf(Pold-LR*gP,sPmin[g]),sPmax[g]);
      sP[g]=Pn; gstore(&ppW[g],Pn);
      const float rtuB=2.f*sB[g], rtdB=0.5f*sB[g];
      sRu[g]=fmaxf(ru-LR*(0.05f*sB[g]+TWO_RHO*(r5-rupS-r9-r11)),0.f);
      sRd[g]=fmaxf(rd-LR*(0.02f*sB[g]+TWO_RHO*(r6-rdnS-r10-r12)),0.f);
      const float duMn=fmaxf(duMo-LR*(INVN*S1s*rtuB+TWO_RHO*( r3+r9 )),0.f);
      const float ddMn=fmaxf(ddMo-LR*(INVN*S1s*rtdB+TWO_RHO*(-r3+r10)),0.f);
      const float dumn=fmaxf(dumo-LR*(INVN*S2s*rtuB+TWO_RHO*( r4+r11)),0.f);
      const float ddmn=fmaxf(ddmo-LR*(INVN*S2s*rtdB+TWO_RHO*(-r4+r12)),0.f);
      sduM[g]=duMn; sddM[g]=ddMn; sdum[g]=dumn; sddm[g]=ddmn;
      pQx=rtuB*duMn+rtdB*ddMn; pQn2=rtuB*dumn+rtdB*ddmn;
      pr3=duMn-ddMn; pr4=dumn-ddmn; pP=Pn;
    }
    blockReduce3(pQx,pQn2,pr3,sRed);
    blockReduce2(pr4,pP,sRed);
    if (tid==0){
      const float LSMn=fmaxf(sScal[3]-LR*(INVN*S1s*VOLL+TWO_RHO*r3),0.f);
      const float SPMn=fmaxf(sScal[4]-LR*(INVN*S1s*VOSP-TWO_RHO*r3),0.f);
      const float LSmn=fmaxf(sScal[5]-LR*(INVN*S2s*VOLL+TWO_RHO*r4),0.f);
      const float SPmn=fmaxf(sScal[6]-LR*(INVN*S2s*VOSP-TWO_RHO*r4),0.f);
      sScal[3]=LSMn; sScal[4]=SPMn; sScal[5]=LSmn; sScal[6]=SPmn;
      gstore(&qsW[0], pQx + VOLL*LSMn + VOSP*SPMn);
      gstore(&qsW[1], pQn2 + VOLL*LSmn + VOSP*SPmn);
      sScal[0]=pr3 + LSMn - SPMn - omaxT;
      sScal[1]=pr4 + LSmn - SPmn - ominT;
      sScal[2]=pP - fctT;
    }
    if (t_own==0 && tid==448)
      gstore(&GAM[(wb*BATCH+b)*PAD], fmaxf(gamma-LR*(epsv-INVN*Sg),0.f));

    // ---- publish epoch k+1: drain own stores to LLC, barrier, set flag ----
    __builtin_amdgcn_s_waitcnt(0);
    __syncthreads();
    if (tid==0) gstoreu(myFlag, (unsigned)(k+2));
  }
}

extern "C" void kernel_launch(void* const* d_in, const int* in_sizes, int n_in,
                              void* d_out, int out_size, void* d_ws, size_t ws_size,
                              hipStream_t stream) {
  const float* forecast = (const float*)d_in[0];
  const float* omega    = (const float*)d_in[1];
  const float* omin     = (const float*)d_in[2];
  const float* omax     = (const float*)d_in[3];
  const float* eps      = (const float*)d_in[4];
  const float* pmin     = (const float*)d_in[5];
  const float* pmax     = (const float*)d_in[6];
  const float* bG       = (const float*)d_in[7];
  const float* cG       = (const float*)d_in[8];
  float* out = (float*)d_out;
  float* ws  = (float*)d_ws;
  void* args[] = { &forecast, &omega, &omin, &omax, &eps, &pmin, &pmax, &bG, &cG, &out, &ws };
  hipLaunchCooperativeKernel((const void*)dro_kernel, dim3(NBLK), dim3(NTHR),
                             args, 0, stream);
}

// Round 8
// 498.393 us; speedup vs baseline: 3.0246x; 1.1183x over previous
//
#include <hip/hip_runtime.h>
#include <hip/hip_cooperative_groups.h>

namespace cg = cooperative_groups;

#define G_ 100
#define T_ 24
#define NSC 128
#define BATCH 8
#define NITER 40
#define NBLK (BATCH*T_)     // 192 WGs: one (batch,t) per WG
#define NTHR 512            // 8 waves -> 2 waves/SIMD
#define GMAX 13
#define PAD 32              // 128B line padding for all cross-WG words

// Relaxed agent-scope atomics -> sc1 LLC-direct ops; no cache-maintenance
// fences. Ordering = s_waitcnt vmcnt(0) + __syncthreads (proven R7 pattern).
__device__ __forceinline__ float gload(const float* p){
  return __hip_atomic_load(p, __ATOMIC_RELAXED, __HIP_MEMORY_SCOPE_AGENT);
}
__device__ __forceinline__ void gstore(float* p, float v){
  __hip_atomic_store(p, v, __ATOMIC_RELAXED, __HIP_MEMORY_SCOPE_AGENT);
}
__device__ __forceinline__ unsigned gloadu(const unsigned* p){
  return __hip_atomic_load(p, __ATOMIC_RELAXED, __HIP_MEMORY_SCOPE_AGENT);
}
__device__ __forceinline__ void gstoreu(unsigned* p, unsigned v){
  __hip_atomic_store(p, v, __ATOMIC_RELAXED, __HIP_MEMORY_SCOPE_AGENT);
}

// full-block reduce (epilogue only)
__device__ __forceinline__ void blockReduce2(float& a, float& b, float* sR){
#pragma unroll
  for (int off=32; off; off>>=1){ a+=__shfl_down(a,off,64); b+=__shfl_down(b,off,64); }
  const int w = threadIdx.x>>6;
  __syncthreads();
  if ((threadIdx.x&63)==0){ sR[w]=a; sR[8+w]=b; }
  __syncthreads();
  a=0.f; b=0.f;
#pragma unroll
  for (int i=0;i<8;++i){ a+=sR[i]; b+=sR[8+i]; }
}

// wave0 polls the 24 per-slice epoch flags (each on its own line)
__device__ __forceinline__ void waitEpoch(const unsigned* flB, unsigned tgt, int tid, int lane){
  if (tid < 64){
    for (;;){
      unsigned f = (lane < T_) ? gloadu(&flB[lane*PAD]) : tgt;
      if (__ballot(f < tgt) == 0ull) break;
      __builtin_amdgcn_s_sleep(1);
    }
  }
  __syncthreads();   // barrier #1
}

__global__ __launch_bounds__(NTHR, 1) void dro_kernel(
    const float* __restrict__ forecast, const float* __restrict__ omega,
    const float* __restrict__ om_min, const float* __restrict__ om_max,
    const float* __restrict__ eps_in, const float* __restrict__ pmin_g,
    const float* __restrict__ pmax_g, const float* __restrict__ bG,
    const float* __restrict__ cG, float* __restrict__ out, float* __restrict__ ws)
{
  constexpr float LR=2e-4f, VOLL=1000.f, VOSP=50.f, TWO_RHO=20.f, INVN=1.f/128.f;
  const int blk=blockIdx.x;
  const int b=blk&7;
  const int t_own=blk>>3;
  const int tid=threadIdx.x, wave=tid>>6, lane=tid&63;
  const int gcnt  = (wave<4)? 13 : 12;
  const int gbase = (wave<4)? wave*13 : 52+(wave-4)*12;

  __shared__ float sRu[G_], sRd[G_];
  __shared__ float sP[G_], sduM[G_], sddM[G_], sdum[G_], sddm[G_];
  __shared__ float sAccU[G_], sAccD[G_];
  __shared__ float sB[G_], sPmin[G_], sPmax[G_], sC[G_];
  __shared__ float sLS[NSC], sSP[NSC], sOm[NSC];
  __shared__ float sGQ[NSC], sR220[NSC];
  __shared__ float sQn[NSC], sDM[NSC], sDm[NSC], sS2[NSC];
  __shared__ float sQp[NSC*9], sSp[NSC*9];     // [n][wave] stride 9 (conflict-free)
  __shared__ float sQnP[NTHR];
  __shared__ float sRed[40];
  __shared__ float sScal[12];  // 0..2: r3,r4,rP ; 3..6: LSM,SPM,LSm,SPm ; 8..10: S1s,S2s,Sg

  // ---- ws layout (floats). Cross-WG scalars padded to 128B lines. ----
  float* QNP = ws;                          // [3][B][24][128]
  float* PP  = ws + 73728;                  // [3][B][24][128] (first 100 used)
  float* QS  = ws + 147456;                 // [3][B][24][PAD]  (Qmax@0, Qmin@1)
  float* GAM = ws + 165888;                 // [3][B][PAD]
  float* ST1 = ws + 166656;                 // [B][24][PAD]
  unsigned* FLG = (unsigned*)(ws + 172800); // [B][24][PAD]

  const float epsv  = eps_in[b];
  const float omaxT = om_max[b*T_ + t_own];
  const float ominT = om_min[b*T_ + t_own];
  const float fctT  = forecast[b*T_ + t_own];
  const unsigned* flB = FLG + b*T_*PAD;
  unsigned* myFlag    = FLG + (b*T_ + t_own)*PAD;

  // register-resident d_up/d_dn: lane holds n=lane (A) and n=lane+64 (B)
  float duA[GMAX], duB[GMAX], ddA[GMAX], ddB[GMAX];

  // ---------------- init ----------------
  if (tid<G_){
    sB[tid]=bG[tid]; sPmin[tid]=pmin_g[tid]; sPmax[tid]=pmax_g[tid]; sC[tid]=cG[tid];
    sRu[tid]=0.f; sRd[tid]=0.f;
    sduM[tid]=0.f; sddM[tid]=0.f; sdum[tid]=0.f; sddm[tid]=0.f;
    sAccU[tid]=0.f; sAccD[tid]=0.f;
  }
  if (tid<NSC){
    const int n=tid;
    sLS[n]=0.f; sSP[n]=0.f; sS2[n]=0.f;
    sOm[n]=omega[(b*NSC+n)*T_+t_own];
    float dM=0.f,dm=0.f;
    for (int t=0;t<T_;++t){
      float o=omega[(b*NSC+n)*T_+t];
      dM+=om_max[b*T_+t]-o; dm+=o-om_min[b*T_+t];
    }
    sDM[n]=dM; sDm[n]=dm;
  }
  if (tid==0){ sScal[3]=0.f; sScal[4]=0.f; sScal[5]=0.f; sScal[6]=0.f; }
  __syncthreads();
#pragma unroll
  for (int j=0;j<GMAX;++j){ duA[j]=0.f; duB[j]=0.f; ddA[j]=0.f; ddB[j]=0.f; }
  {
    float p0=0.f;
    if (tid<G_){
      p0=0.5f*(sPmin[tid]+sPmax[tid]);
      sP[tid]=p0;
      gstore(&PP[b*3072 + t_own*NSC + tid], p0);
    }
    if (tid<NSC) gstore(&QNP[b*3072 + t_own*NSC + tid], 0.f);
    if (tid<2)   gstore(&QS[(b*T_ + t_own)*PAD + tid], 0.f);
    if (t_own==0 && tid==0) gstore(&GAM[b*PAD], 0.f);
    float rp=p0, dum0=0.f;
    blockReduce2(rp,dum0,sRed);
    if (tid==0){
      sScal[0]=-omaxT; sScal[1]=-ominT; sScal[2]=rp-fctT;
      gstoreu(myFlag, 1u);
    }
  }
  __builtin_amdgcn_s_waitcnt(0);
  cg::this_grid().sync();   // one-time

  for (int k=0;k<=NITER;++k){
    waitEpoch(flB, (unsigned)(k+1), tid, lane);   // barrier #1

    const int rb = k%3, wb = (k+1)%3;
    const float* qnpR = QNP + rb*24576 + b*3072;
    const float* ppR  = PP  + rb*24576 + b*3072;
    const float* qsR  = QS  + (rb*BATCH + b)*T_*PAD;
    float* qnpW = QNP + wb*24576 + b*3072 + t_own*NSC;
    float* ppW  = PP  + wb*24576 + b*3072 + t_own*NSC;
    float* qsW  = QS  + (wb*BATCH + b)*T_*PAD + t_own*PAD;

    const float gamma = gload(&GAM[(rb*BATCH + b)*PAD]);
    float pm1=0.f, pp1=0.f;
    if (tid<G_){
      if (t_own>0)     pm1 = gload(&ppR[(t_own-1)*NSC + tid]);
      if (t_own<T_-1)  pp1 = gload(&ppR[(t_own+1)*NSC + tid]);
    }
    {
      const int n = tid&127, sb0 = (tid>>7)*6;
      float q=0.f;
#pragma unroll
      for (int s=0;s<6;++s) q += gload(&qnpR[(sb0+s)*NSC + n]);
      sQnP[tid]=q;
    }
    float Qmax = (tid<T_)? gload(&qsR[tid*PAD])   : 0.f;
    float Qmin = (tid<T_)? gload(&qsR[tid*PAD+1]) : 0.f;

    if (k==NITER){  // ---------------- final: phi + outputs ----------------
      blockReduce2(Qmax,Qmin,sRed);   // also publishes sQnP
      if (tid<NSC){
        const int n=tid;
        const float qsum=sQnP[n]+sQnP[n+128]+sQnP[n+256]+sQnP[n+384];
        const float m1=Qmax-gamma*sDM[n], m2=Qmin-gamma*sDm[n];
        const float ph=fmaxf(qsum,fmaxf(m1,m2));
        sQn[n]=ph;
        if (t_own==0) out[76800 + b*NSC + n]=ph;
      }
      float st=0.f, dum0=0.f;
      if (tid<G_){
        const int g=tid;
        const float Pv=sP[g];
        const float costv=sB[g]*Pv+sC[g];
        st=costv + 0.05f*sB[g]*sRu[g] + 0.02f*sB[g]*sRd[g];
        const int o=b*2400 + g*T_ + t_own;
        out[o]=Pv;
        out[19200+o]=sRu[g];
        out[38400+o]=sRd[g];
        out[57600+o]=costv;
      }
      blockReduce2(st,dum0,sRed);
      if (tid==0) gstore(&ST1[(b*T_+t_own)*PAD], st);
      if (t_own==0 && tid==0) out[77824+b]=gamma;
      __builtin_amdgcn_s_waitcnt(0);
      __syncthreads();
      if (tid==0) gstoreu(myFlag, (unsigned)(NITER+2));
      if (t_own==0){
        waitEpoch(flB, (unsigned)(NITER+2), tid, lane);
        float pm = (tid<NSC)? sQn[tid] : 0.f;
        float s1 = (tid<T_)? gload(&ST1[(b*T_+tid)*PAD]) : 0.f;
        blockReduce2(pm,s1,sRed);
        if (tid==0) out[77832+b] = s1 + pm*INVN + epsv*gamma;
      }
      break;
    }

    __syncthreads();   // barrier #2: publish sQnP (Qmax lanes are wave0-local)

    // ---- wave0 only: Qmax/Qmin butterfly + weights + LS/SP + S-sums ----
    if (wave==0){
#pragma unroll
      for (int off=32; off; off>>=1){ Qmax+=__shfl_xor(Qmax,off,64); Qmin+=__shfl_xor(Qmin,off,64); }
      float g1l=0.f,g2l=0.f,sgl=0.f;
#pragma unroll
      for (int h=0;h<2;++h){
        const int n=lane+h*64;
        const float Qn=sQnP[n]+sQnP[n+128]+sQnP[n+256]+sQnP[n+384];
        const float m1=Qmax-gamma*sDM[n], m2=Qmin-gamma*sDm[n];
        const float inner=fmaxf(m1,m2), ph=fmaxf(Qn,inner);
        const float gQn=(Qn==ph?1.f:0.f)/((inner==ph)?2.f:1.f);
        const float gIn=(inner==ph?1.f:0.f)/((Qn==ph)?2.f:1.f);
        const float gm1=gIn*(m1==inner?1.f:0.f)/((m2==inner)?2.f:1.f);
        const float gm2=gIn*(m2==inner?1.f:0.f)/((m1==inner)?2.f:1.f);
        const float gq=gQn*INVN;
        sGQ[n]=gq;
        g1l+=gm1; g2l+=gm2; sgl+=gm1*sDM[n]+gm2*sDm[n];
        const float r2=sS2[n]+sLS[n]-sSP[n]-sOm[n];
        const float r220=TWO_RHO*r2;
        sR220[n]=r220;
        sLS[n]=fmaxf(sLS[n]-LR*(gq*VOLL+r220),0.f);
        sSP[n]=fmaxf(sSP[n]-LR*(gq*VOSP-r220),0.f);
      }
#pragma unroll
      for (int off=32; off; off>>=1){
        g1l+=__shfl_xor(g1l,off,64); g2l+=__shfl_xor(g2l,off,64); sgl+=__shfl_xor(sgl,off,64);
      }
      if (lane==0){ sScal[8]=g1l; sScal[9]=g2l; sScal[10]=sgl; }
    }
    __syncthreads();   // barrier #3: publish sGQ/sR220/sLS/sSP/sScal[8..10]

    // ---- pass A: d update + produce partials (no shuffles; acc precomputed) ----
    const float gqA=sGQ[lane],    r220A=sR220[lane];
    const float gqB=sGQ[lane+64], r220B=sR220[lane+64];
    float qvA=0.f,qvB=0.f,svA=0.f,svB=0.f;
#pragma unroll
    for (int j=0;j<GMAX;++j){
      if (j<gcnt){
        const int g=gbase+j;
        const float bg=sB[g];
        const float rtu=2.f*bg, rtd=0.5f*bg;
        const float ru=sRu[g], rd=sRd[g];
        const float r7A=fmaxf(duA[j]-ru,0.f), r8A=fmaxf(ddA[j]-rd,0.f);
        const float r7B=fmaxf(duB[j]-ru,0.f), r8B=fmaxf(ddB[j]-rd,0.f);
        duA[j]=fmaxf(duA[j]-LR*(gqA*rtu+(r220A+TWO_RHO*r7A)),0.f);
        ddA[j]=fmaxf(ddA[j]-LR*(gqA*rtd+(TWO_RHO*r8A-r220A)),0.f);
        duB[j]=fmaxf(duB[j]-LR*(gqB*rtu+(r220B+TWO_RHO*r7B)),0.f);
        ddB[j]=fmaxf(ddB[j]-LR*(gqB*rtd+(TWO_RHO*r8B-r220B)),0.f);
        qvA+=rtu*duA[j]+rtd*ddA[j];  svA+=duA[j]-ddA[j];
        qvB+=rtu*duB[j]+rtd*ddB[j];  svB+=duB[j]-ddB[j];
      }
    }
    sQp[lane*9+wave]=qvA;      sSp[lane*9+wave]=svA;
    sQp[(lane+64)*9+wave]=qvB; sSp[(lane+64)*9+wave]=svB;
    __syncthreads();   // barrier #4

    // ---- combine (waves 4-5) | pass B (tid<100) | gamma (tid 448) ----
    if (tid>=256 && tid<384){
      const int n=tid-256;
      float q=0.f,s=0.f;
#pragma unroll
      for (int w=0;w<8;++w){ q+=sQp[n*9+w]; s+=sSp[n*9+w]; }
      sS2[n]=s;
      q += VOLL*sLS[n]+VOSP*sSP[n];
      gstore(&qnpW[n], q);
    }
    const float r3=sScal[0], r4=sScal[1], rP=sScal[2];
    const float S1s=sScal[8], S2s=sScal[9];
    float pQx=0.f,pQn2=0.f,pr3=0.f,pr4=0.f,pP=0.f;
    if (tid<G_){
      const int g=tid;
      const float rupS=sAccU[g], rdnS=sAccD[g];
      const float Pold=sP[g], ru=sRu[g], rd=sRd[g];
      const float duMo=sduM[g], ddMo=sddM[g], dumo=sdum[g], ddmo=sddm[g];
      const float r5 =fmaxf(Pold+ru-sPmax[g],0.f);
      const float r6 =fmaxf(sPmin[g]-Pold+rd,0.f);
      const float r9 =fmaxf(duMo-ru,0.f), r10=fmaxf(ddMo-rd,0.f);
      const float r11=fmaxf(dumo-ru,0.f), r12=fmaxf(ddmo-rd,0.f);
      const float rampg=sPmax[g];
      float gP=sB[g]+TWO_RHO*(rP+r5-r6);
      if (t_own>0){
        const float dp=Pold-pm1;
        gP+=TWO_RHO*fmaxf(fabsf(dp)-rampg,0.f)*(dp>=0.f?1.f:-1.f);
      }
      if (t_own<T_-1){
        const float dq=pp1-Pold;
        gP-=TWO_RHO*fmaxf(fabsf(dq)-rampg,0.f)*(dq>=0.f?1.f:-1.f);
      }
      const float Pn=fminf(fmaxf(Pold-LR*gP,sPmin[g]),sPmax[g]);
      sP[g]=Pn; gstore(&ppW[g],Pn);
      const float rtuB=2.f*sB[g], rtdB=0.5f*sB[g];
      sRu[g]=fmaxf(ru-LR*(0.05f*sB[g]+TWO_RHO*(r5-rupS-r9-r11)),0.f);
      sRd[g]=fmaxf(rd-LR*(0.02f*sB[g]+TWO_RHO*(r6-rdnS-r10-r12)),0.f);
      const float duMn=fmaxf(duMo-LR*(INVN*S1s*rtuB+TWO_RHO*( r3+r9 )),0.f);
      const float ddMn=fmaxf(ddMo-LR*(INVN*S1s*rtdB+TWO_RHO*(-r3+r10)),0.f);
      const float dumn=fmaxf(dumo-LR*(INVN*S2s*rtuB+TWO_RHO*( r4+r11)),0.f);
      const float ddmn=fmaxf(ddmo-LR*(INVN*S2s*rtdB+TWO_RHO*(-r4+r12)),0.f);
      sduM[g]=duMn; sddM[g]=ddMn; sdum[g]=dumn; sddm[g]=ddmn;
      pQx=rtuB*duMn+rtdB*ddMn; pQn2=rtuB*dumn+rtdB*ddmn;
      pr3=duMn-ddMn; pr4=dumn-ddmn; pP=Pn;
    }
    if (t_own==0 && tid==448)
      gstore(&GAM[(wb*BATCH+b)*PAD], fmaxf(gamma-LR*(epsv-INVN*sScal[10]),0.f));

    // merged 5-value reduction: per-wave shuffle + leader writes
#pragma unroll
    for (int off=32; off; off>>=1){
      pQx+=__shfl_down(pQx,off,64);  pQn2+=__shfl_down(pQn2,off,64);
      pr3+=__shfl_down(pr3,off,64);  pr4+=__shfl_down(pr4,off,64);
      pP +=__shfl_down(pP,off,64);
    }
    if (lane==0){
      sRed[wave]=pQx; sRed[8+wave]=pQn2; sRed[16+wave]=pr3;
      sRed[24+wave]=pr4; sRed[32+wave]=pP;
    }
    __builtin_amdgcn_s_waitcnt(0);   // drain qnpW/ppW/gamma stores (per wave)
    __syncthreads();   // barrier #5

    if (tid==0){
      float aQx=0.f,aQn2=0.f,a3=0.f,a4=0.f,aP=0.f;
#pragma unroll
      for (int i=0;i<8;++i){
        aQx+=sRed[i]; aQn2+=sRed[8+i]; a3+=sRed[16+i]; a4+=sRed[24+i]; aP+=sRed[32+i];
      }
      const float LSMn=fmaxf(sScal[3]-LR*(INVN*S1s*VOLL+TWO_RHO*r3),0.f);
      const float SPMn=fmaxf(sScal[4]-LR*(INVN*S1s*VOSP-TWO_RHO*r3),0.f);
      const float LSmn=fmaxf(sScal[5]-LR*(INVN*S2s*VOLL+TWO_RHO*r4),0.f);
      const float SPmn=fmaxf(sScal[6]-LR*(INVN*S2s*VOSP-TWO_RHO*r4),0.f);
      sScal[3]=LSMn; sScal[4]=SPMn; sScal[5]=LSmn; sScal[6]=SPmn;
      gstore(&qsW[0], aQx + VOLL*LSMn + VOSP*SPMn);
      gstore(&qsW[1], aQn2 + VOLL*LSmn + VOSP*SPmn);
      sScal[0]=a3 + LSMn - SPMn - omaxT;
      sScal[1]=a4 + LSmn - SPmn - ominT;
      sScal[2]=aP - fctT;
    }
    __builtin_amdgcn_s_waitcnt(0);   // drain tid0's qsW stores (wave0)
    __syncthreads();   // barrier #6: orders data stores before flag
    if (tid==0) gstoreu(myFlag, (unsigned)(k+2));

    // ---- shadow precompute (in wait window): accU/accD for next iter ----
#pragma unroll
    for (int j=0;j<GMAX;++j){
      if (j<gcnt){
        const int g=gbase+j;
        const float ru=sRu[g], rd=sRd[g];
        float aU=fmaxf(duA[j]-ru,0.f)+fmaxf(duB[j]-ru,0.f);
        float aD=fmaxf(ddA[j]-rd,0.f)+fmaxf(ddB[j]-rd,0.f);
#pragma unroll
        for (int off=32; off; off>>=1){ aU+=__shfl_xor(aU,off,64); aD+=__shfl_xor(aD,off,64); }
        if (lane==0){ sAccU[g]=aU; sAccD[g]=aD; }
      }
    }
  }
}

extern "C" void kernel_launch(void* const* d_in, const int* in_sizes, int n_in,
                              void* d_out, int out_size, void* d_ws, size_t ws_size,
                              hipStream_t stream) {
  const float* forecast = (const float*)d_in[0];
  const float* omega    = (const float*)d_in[1];
  const float* omin     = (const float*)d_in[2];
  const float* omax     = (const float*)d_in[3];
  const float* eps      = (const float*)d_in[4];
  const float* pmin     = (const float*)d_in[5];
  const float* pmax     = (const float*)d_in[6];
  const float* bG       = (const float*)d_in[7];
  const float* cG       = (const float*)d_in[8];
  float* out = (float*)d_out;
  float* ws  = (float*)d_ws;
  void* args[] = { &forecast, &omega, &omin, &omax, &eps, &pmin, &pmax, &bG, &cG, &out, &ws };
  hipLaunchCooperativeKernel((const void*)dro_kernel, dim3(NBLK), dim3(NTHR),
                             args, 0, stream);
}

// Round 9
// 476.113 us; speedup vs baseline: 3.1662x; 1.0468x over previous
//
#include <hip/hip_runtime.h>
#include <hip/hip_cooperative_groups.h>

namespace cg = cooperative_groups;

#define G_ 100
#define T_ 24
#define NSC 128
#define BATCH 8
#define NITER 40
#define NBLK (BATCH*T_)     // 192 WGs: one (batch,t) per WG
#define NTHR 512            // 8 waves -> 2 waves/SIMD
#define GMAX 13

typedef unsigned long long u64;

// All cross-WG words are (tag<<32 | float) pairs, stored/loaded with single
// atomic 8B relaxed agent-scope ops (sc1 -> LLC-direct). Consumers spin on
// the tag; producers never fence/drain. Depth-3 buffers + monotonic tags.
__device__ __forceinline__ u64 gload64(const u64* p){
  return __hip_atomic_load(p, __ATOMIC_RELAXED, __HIP_MEMORY_SCOPE_AGENT);
}
__device__ __forceinline__ void gstore64(u64* p, u64 v){
  __hip_atomic_store(p, v, __ATOMIC_RELAXED, __HIP_MEMORY_SCOPE_AGENT);
}
__device__ __forceinline__ u64 pack(float v, unsigned tag){
  return ((u64)tag<<32) | (u64)__float_as_uint(v);
}
__device__ __forceinline__ float unpackv(u64 x){ return __uint_as_float((unsigned)x); }
__device__ __forceinline__ unsigned unpackt(u64 x){ return (unsigned)(x>>32); }

// full-block reduce (init/epilogue only)
__device__ __forceinline__ void blockReduce2(float& a, float& b, float* sR){
#pragma unroll
  for (int off=32; off; off>>=1){ a+=__shfl_down(a,off,64); b+=__shfl_down(b,off,64); }
  const int w = threadIdx.x>>6;
  __syncthreads();
  if ((threadIdx.x&63)==0){ sR[w]=a; sR[8+w]=b; }
  __syncthreads();
  a=0.f; b=0.f;
#pragma unroll
  for (int i=0;i<8;++i){ a+=sR[i]; b+=sR[8+i]; }
}

__global__ __launch_bounds__(NTHR, 1) void dro_kernel(
    const float* __restrict__ forecast, const float* __restrict__ omega,
    const float* __restrict__ om_min, const float* __restrict__ om_max,
    const float* __restrict__ eps_in, const float* __restrict__ pmin_g,
    const float* __restrict__ pmax_g, const float* __restrict__ bG,
    const float* __restrict__ cG, float* __restrict__ out, float* __restrict__ ws)
{
  constexpr float LR=2e-4f, VOLL=1000.f, VOSP=50.f, TWO_RHO=20.f, INVN=1.f/128.f;
  const int blk=blockIdx.x;
  const int b=blk&7;
  const int t_own=blk>>3;
  const int tid=threadIdx.x, wave=tid>>6, lane=tid&63;
  const int gcnt  = (wave<4)? 13 : 12;
  const int gbase = (wave<4)? wave*13 : 52+(wave-4)*12;

  __shared__ float sRu[G_], sRd[G_];
  __shared__ float sP[G_], sduM[G_], sddM[G_], sdum[G_], sddm[G_];
  __shared__ float sAccU[G_], sAccD[G_];
  __shared__ float sB[G_], sPmin[G_], sPmax[G_], sC[G_];
  __shared__ float sLS[NSC], sSP[NSC], sOm[NSC];
  __shared__ float sGQ[NSC], sR220[NSC];
  __shared__ float sQn[NSC], sDM[NSC], sDm[NSC], sS2[NSC];
  __shared__ float sQp[NSC*9], sSp[NSC*9];     // [n][wave] stride 9 (conflict-free)
  __shared__ float sQnP[NTHR];
  __shared__ float sRed[40];
  __shared__ float sScal[12];  // 0..2 r3,r4,rP ; 3..6 LSM,SPM,LSm,SPm ; 8,9 Qmax,Qmin(fin) ; 11 gamma

  // ---- ws layout in u64 units; pairs on natural 8B alignment ----
  u64* W = (u64*)ws;
  u64* QNP = W;                       // [3][8][24][128]
  u64* PP  = W + 73728;               // [3][8][24][128] (first 100 used)
  u64* QS  = W + 147456;              // [3][8][24][16]  (Qmax@0, Qmin@1)
  u64* GAM = W + 156672;              // [3][8][16]
  u64* ST1 = W + 157056;              // [8][24][16]
                                      // end: 160128 u64 = 1.28 MB

  const float epsv  = eps_in[b];
  const float omaxT = om_max[b*T_ + t_own];
  const float ominT = om_min[b*T_ + t_own];
  const float fctT  = forecast[b*T_ + t_own];

  // register-resident d_up/d_dn: lane holds n=lane (A) and n=lane+64 (B)
  float duA[GMAX], duB[GMAX], ddA[GMAX], ddB[GMAX];

  // ---------------- init ----------------
  if (tid<G_){
    sB[tid]=bG[tid]; sPmin[tid]=pmin_g[tid]; sPmax[tid]=pmax_g[tid]; sC[tid]=cG[tid];
    sRu[tid]=0.f; sRd[tid]=0.f;
    sduM[tid]=0.f; sddM[tid]=0.f; sdum[tid]=0.f; sddm[tid]=0.f;
    sAccU[tid]=0.f; sAccD[tid]=0.f;
  }
  if (tid<NSC){
    const int n=tid;
    sLS[n]=0.f; sSP[n]=0.f; sS2[n]=0.f;
    sOm[n]=omega[(b*NSC+n)*T_+t_own];
    float dM=0.f,dm=0.f;
    for (int t=0;t<T_;++t){
      float o=omega[(b*NSC+n)*T_+t];
      dM+=om_max[b*T_+t]-o; dm+=o-om_min[b*T_+t];
    }
    sDM[n]=dM; sDm[n]=dm;
  }
  if (tid==0){ sScal[3]=0.f; sScal[4]=0.f; sScal[5]=0.f; sScal[6]=0.f; }
  __syncthreads();
#pragma unroll
  for (int j=0;j<GMAX;++j){ duA[j]=0.f; duB[j]=0.f; ddA[j]=0.f; ddB[j]=0.f; }
  {
    float p0=0.f;
    if (tid<G_){
      p0=0.5f*(sPmin[tid]+sPmax[tid]);
      sP[tid]=p0;
      gstore64(&PP[b*3072 + t_own*128 + tid], pack(p0,1u));
    }
    if (tid<NSC) gstore64(&QNP[b*3072 + t_own*128 + tid], pack(0.f,1u));
    if (tid<2)   gstore64(&QS[(b*T_ + t_own)*16 + tid], pack(0.f,1u));
    if (t_own==0 && tid==0) gstore64(&GAM[b*16], pack(0.f,1u));
    float rp=p0, dum0=0.f;
    blockReduce2(rp,dum0,sRed);
    if (tid==0){
      sScal[0]=-omaxT; sScal[1]=-ominT; sScal[2]=rp-fctT;
    }
  }
  __syncthreads();
  // no grid sync needed: 0xAA-poisoned ws never matches a tag; consumers spin.

  for (int k=0;k<=NITER;++k){
    const unsigned tg = (unsigned)(k+1);
    const int rb = k%3, wb = (k+1)%3;
    const u64* qnpR = QNP + rb*24576 + b*3072;
    const u64* ppR  = PP  + rb*24576 + b*3072;
    const u64* qsR  = QS  + (rb*BATCH + b)*T_*16;
    const u64* gamR = GAM + (rb*BATCH + b)*16;
    u64* qnpW = QNP + wb*24576 + b*3072 + t_own*128;
    u64* ppW  = PP  + wb*24576 + b*3072 + t_own*128;
    u64* qsW  = QS  + (wb*BATCH + b)*T_*16 + t_own*16;
    u64* gamW = GAM + (wb*BATCH + b)*16;

    // ---- consume: issue everything, then spin on tags ----
    const int n = tid&127, sb0 = (tid>>7)*6;
    u64 xq[6];
#pragma unroll
    for (int s=0;s<6;++s) xq[s]=gload64(&qnpR[(sb0+s)*128 + n]);
    u64 xm=0, xp=0;
    if (tid<G_){
      if (t_own>0)     xm = gload64(&ppR[(t_own-1)*128 + tid]);
      if (t_own<T_-1)  xp = gload64(&ppR[(t_own+1)*128 + tid]);
    }
    u64 xs0=0, xs1=0, xg=0;
    if (wave==0){
      if (lane<T_){ xs0=gload64(&qsR[lane*16]); xs1=gload64(&qsR[lane*16+1]); }
      xg=gload64(gamR);
    }
    for (;;){
      bool any=false;
#pragma unroll
      for (int s=0;s<6;++s)
        if (unpackt(xq[s])!=tg){ any=true; xq[s]=gload64(&qnpR[(sb0+s)*128 + n]); }
      if (!any) break;
      __builtin_amdgcn_s_sleep(1);
    }
    if (tid<G_){
      if (t_own>0)    while (unpackt(xm)!=tg){ __builtin_amdgcn_s_sleep(1); xm=gload64(&ppR[(t_own-1)*128 + tid]); }
      if (t_own<T_-1) while (unpackt(xp)!=tg){ __builtin_amdgcn_s_sleep(1); xp=gload64(&ppR[(t_own+1)*128 + tid]); }
    }
    float Qmax=0.f, Qmin=0.f, gamma=0.f;
    if (wave==0){
      if (lane<T_){
        while (unpackt(xs0)!=tg){ __builtin_amdgcn_s_sleep(1); xs0=gload64(&qsR[lane*16]); }
        while (unpackt(xs1)!=tg){ __builtin_amdgcn_s_sleep(1); xs1=gload64(&qsR[lane*16+1]); }
        Qmax=unpackv(xs0); Qmin=unpackv(xs1);
      }
      while (unpackt(xg)!=tg){ __builtin_amdgcn_s_sleep(1); xg=gload64(gamR); }
      gamma=unpackv(xg);
      if (lane==0) sScal[11]=gamma;
    }
    sQnP[tid]=unpackv(xq[0])+unpackv(xq[1])+unpackv(xq[2])
             +unpackv(xq[3])+unpackv(xq[4])+unpackv(xq[5]);
    const float pm1=unpackv(xm), pp1=unpackv(xp);
    __syncthreads();   // barrier A: sQnP + sScal[11] published; all data valid

    if (k==NITER){  // ---------------- final: phi + outputs ----------------
      if (wave==0){
#pragma unroll
        for (int off=32; off; off>>=1){ Qmax+=__shfl_xor(Qmax,off,64); Qmin+=__shfl_xor(Qmin,off,64); }
        if (lane==0){ sScal[8]=Qmax; sScal[9]=Qmin; }
      }
      __syncthreads();
      const float Qm=sScal[8], Qn2=sScal[9], gam=sScal[11];
      if (tid<NSC){
        const float qsum=sQnP[tid]+sQnP[tid+128]+sQnP[tid+256]+sQnP[tid+384];
        const float ph=fmaxf(qsum,fmaxf(Qm-gam*sDM[tid],Qn2-gam*sDm[tid]));
        sQn[tid]=ph;
        if (t_own==0) out[76800 + b*NSC + tid]=ph;
      }
      float st=0.f, dum0=0.f;
      if (tid<G_){
        const int g=tid;
        const float Pv=sP[g];
        const float costv=sB[g]*Pv+sC[g];
        st=costv + 0.05f*sB[g]*sRu[g] + 0.02f*sB[g]*sRd[g];
        const int o=b*2400 + g*T_ + t_own;
        out[o]=Pv;
        out[19200+o]=sRu[g];
        out[38400+o]=sRd[g];
        out[57600+o]=costv;
      }
      blockReduce2(st,dum0,sRed);
      if (tid==0) gstore64(&ST1[(b*T_+t_own)*16], pack(st,99u));
      if (t_own==0){
        if (tid==0) out[77824+b]=gam;
        float s1=0.f;
        if (tid<64){
          u64 xs = (lane<T_)? gload64(&ST1[(b*T_+lane)*16]) : pack(0.f,99u);
          while (unpackt(xs)!=99u){ __builtin_amdgcn_s_sleep(1); xs=gload64(&ST1[(b*T_+lane)*16]); }
          s1=unpackv(xs);
        }
        float pm=(tid<NSC)? sQn[tid] : 0.f;
        blockReduce2(pm,s1,sRed);
        if (tid==0) out[77832+b] = s1 + pm*INVN + epsv*gam;
      }
      break;
    }

    // ---- wave0: Qmax/Qmin butterfly + weights + LS/SP + S-sums ----
    if (wave==0){
#pragma unroll
      for (int off=32; off; off>>=1){ Qmax+=__shfl_xor(Qmax,off,64); Qmin+=__shfl_xor(Qmin,off,64); }
      float g1l=0.f,g2l=0.f,sgl=0.f;
#pragma unroll
      for (int h=0;h<2;++h){
        const int nn=lane+h*64;
        const float Qn=sQnP[nn]+sQnP[nn+128]+sQnP[nn+256]+sQnP[nn+384];
        const float m1=Qmax-gamma*sDM[nn], m2=Qmin-gamma*sDm[nn];
        const float inner=fmaxf(m1,m2), ph=fmaxf(Qn,inner);
        const float gQn=(Qn==ph?1.f:0.f)/((inner==ph)?2.f:1.f);
        const float gIn=(inner==ph?1.f:0.f)/((Qn==ph)?2.f:1.f);
        const float gm1=gIn*(m1==inner?1.f:0.f)/((m2==inner)?2.f:1.f);
        const float gm2=gIn*(m2==inner?1.f:0.f)/((m1==inner)?2.f:1.f);
        const float gq=gQn*INVN;
        sGQ[nn]=gq;
        g1l+=gm1; g2l+=gm2; sgl+=gm1*sDM[nn]+gm2*sDm[nn];
        const float r2=sS2[nn]+sLS[nn]-sSP[nn]-sOm[nn];
        const float r220=TWO_RHO*r2;
        sR220[nn]=r220;
        sLS[nn]=fmaxf(sLS[nn]-LR*(gq*VOLL+r220),0.f);
        sSP[nn]=fmaxf(sSP[nn]-LR*(gq*VOSP-r220),0.f);
      }
#pragma unroll
      for (int off=32; off; off>>=1){
        g1l+=__shfl_xor(g1l,off,64); g2l+=__shfl_xor(g2l,off,64); sgl+=__shfl_xor(sgl,off,64);
      }
      if (lane==0){ sScal[8]=g1l; sScal[9]=g2l; sScal[10]=sgl; }
    }
    __syncthreads();   // barrier B

    // ---- pass A: d update + produce partials (acc precomputed in shadow) ----
    const float gqA=sGQ[lane],    r220A=sR220[lane];
    const float gqB=sGQ[lane+64], r220B=sR220[lane+64];
    float qvA=0.f,qvB=0.f,svA=0.f,svB=0.f;
#pragma unroll
    for (int j=0;j<GMAX;++j){
      if (j<gcnt){
        const int g=gbase+j;
        const float bg=sB[g];
        const float rtu=2.f*bg, rtd=0.5f*bg;
        const float ru=sRu[g], rd=sRd[g];
        const float r7A=fmaxf(duA[j]-ru,0.f), r8A=fmaxf(ddA[j]-rd,0.f);
        const float r7B=fmaxf(duB[j]-ru,0.f), r8B=fmaxf(ddB[j]-rd,0.f);
        duA[j]=fmaxf(duA[j]-LR*(gqA*rtu+(r220A+TWO_RHO*r7A)),0.f);
        ddA[j]=fmaxf(ddA[j]-LR*(gqA*rtd+(TWO_RHO*r8A-r220A)),0.f);
        duB[j]=fmaxf(duB[j]-LR*(gqB*rtu+(r220B+TWO_RHO*r7B)),0.f);
        ddB[j]=fmaxf(ddB[j]-LR*(gqB*rtd+(TWO_RHO*r8B-r220B)),0.f);
        qvA+=rtu*duA[j]+rtd*ddA[j];  svA+=duA[j]-ddA[j];
        qvB+=rtu*duB[j]+rtd*ddB[j];  svB+=duB[j]-ddB[j];
      }
    }
    sQp[lane*9+wave]=qvA;      sSp[lane*9+wave]=svA;
    sQp[(lane+64)*9+wave]=qvB; sSp[(lane+64)*9+wave]=svB;
    __syncthreads();   // barrier C

    // ---- combine (waves 4-5) | pass B (tid<100) | gamma (tid 448) ----
    const unsigned tg2 = (unsigned)(k+2);
    if (tid>=256 && tid<384){
      const int nn=tid-256;
      float q=0.f,s=0.f;
#pragma unroll
      for (int w=0;w<8;++w){ q+=sQp[nn*9+w]; s+=sSp[nn*9+w]; }
      sS2[nn]=s;
      q += VOLL*sLS[nn]+VOSP*sSP[nn];
      gstore64(&qnpW[nn], pack(q,tg2));
    }
    const float r3=sScal[0], r4=sScal[1], rP=sScal[2];
    const float S1s=sScal[8], S2s=sScal[9];
    float pQx=0.f,pQn2=0.f,pr3=0.f,pr4=0.f,pP=0.f;
    if (tid<G_){
      const int g=tid;
      const float rupS=sAccU[g], rdnS=sAccD[g];
      const float Pold=sP[g], ru=sRu[g], rd=sRd[g];
      const float duMo=sduM[g], ddMo=sddM[g], dumo=sdum[g], ddmo=sddm[g];
      const float r5 =fmaxf(Pold+ru-sPmax[g],0.f);
      const float r6 =fmaxf(sPmin[g]-Pold+rd,0.f);
      const float r9 =fmaxf(duMo-ru,0.f), r10=fmaxf(ddMo-rd,0.f);
      const float r11=fmaxf(dumo-ru,0.f), r12=fmaxf(ddmo-rd,0.f);
      const float rampg=sPmax[g];
      float gP=sB[g]+TWO_RHO*(rP+r5-r6);
      if (t_own>0){
        const float dp=Pold-pm1;
        gP+=TWO_RHO*fmaxf(fabsf(dp)-rampg,0.f)*(dp>=0.f?1.f:-1.f);
      }
      if (t_own<T_-1){
        const float dq=pp1-Pold;
        gP-=TWO_RHO*fmaxf(fabsf(dq)-rampg,0.f)*(dq>=0.f?1.f:-1.f);
      }
      const float Pn=fminf(fmaxf(Pold-LR*gP,sPmin[g]),sPmax[g]);
      sP[g]=Pn; gstore64(&ppW[g], pack(Pn,tg2));
      const float rtuB=2.f*sB[g], rtdB=0.5f*sB[g];
      sRu[g]=fmaxf(ru-LR*(0.05f*sB[g]+TWO_RHO*(r5-rupS-r9-r11)),0.f);
      sRd[g]=fmaxf(rd-LR*(0.02f*sB[g]+TWO_RHO*(r6-rdnS-r10-r12)),0.f);
      const float duMn=fmaxf(duMo-LR*(INVN*S1s*rtuB+TWO_RHO*( r3+r9 )),0.f);
      const float ddMn=fmaxf(ddMo-LR*(INVN*S1s*rtdB+TWO_RHO*(-r3+r10)),0.f);
      const float dumn=fmaxf(dumo-LR*(INVN*S2s*rtuB+TWO_RHO*( r4+r11)),0.f);
      const float ddmn=fmaxf(ddmo-LR*(INVN*S2s*rtdB+TWO_RHO*(-r4+r12)),0.f);
      sduM[g]=duMn; sddM[g]=ddMn; sdum[g]=dumn; sddm[g]=ddmn;
      pQx=rtuB*duMn+rtdB*ddMn; pQn2=rtuB*dumn+rtdB*ddmn;
      pr3=duMn-ddMn; pr4=dumn-ddmn; pP=Pn;
    }
    if (t_own==0 && tid==448)
      gstore64(gamW, pack(fmaxf(sScal[11]-LR*(epsv-INVN*sScal[10]),0.f), tg2));

    // merged 5-value reduction: per-wave shuffle + leader writes
#pragma unroll
    for (int off=32; off; off>>=1){
      pQx+=__shfl_down(pQx,off,64);  pQn2+=__shfl_down(pQn2,off,64);
      pr3+=__shfl_down(pr3,off,64);  pr4+=__shfl_down(pr4,off,64);
      pP +=__shfl_down(pP,off,64);
    }
    if (lane==0){
      sRed[wave]=pQx; sRed[8+wave]=pQn2; sRed[16+wave]=pr3;
      sRed[24+wave]=pr4; sRed[32+wave]=pP;
    }
    __syncthreads();   // barrier D

    if (tid==0){
      float aQx=0.f,aQn2=0.f,a3=0.f,a4=0.f,aP=0.f;
#pragma unroll
      for (int i=0;i<8;++i){
        aQx+=sRed[i]; aQn2+=sRed[8+i]; a3+=sRed[16+i]; a4+=sRed[24+i]; aP+=sRed[32+i];
      }
      const float LSMn=fmaxf(sScal[3]-LR*(INVN*S1s*VOLL+TWO_RHO*r3),0.f);
      const float SPMn=fmaxf(sScal[4]-LR*(INVN*S1s*VOSP-TWO_RHO*r3),0.f);
      const float LSmn=fmaxf(sScal[5]-LR*(INVN*S2s*VOLL+TWO_RHO*r4),0.f);
      const float SPmn=fmaxf(sScal[6]-LR*(INVN*S2s*VOSP-TWO_RHO*r4),0.f);
      sScal[3]=LSMn; sScal[4]=SPMn; sScal[5]=LSmn; sScal[6]=SPmn;
      gstore64(&qsW[0], pack(aQx + VOLL*LSMn + VOSP*SPMn, tg2));
      gstore64(&qsW[1], pack(aQn2 + VOLL*LSmn + VOSP*SPmn, tg2));
      sScal[0]=a3 + LSMn - SPMn - omaxT;
      sScal[1]=a4 + LSmn - SPmn - ominT;
      sScal[2]=aP - fctT;
    }

    // ---- shadow precompute (hidden in next consume's wait): accU/accD ----
#pragma unroll
    for (int j=0;j<GMAX;++j){
      if (j<gcnt){
        const int g=gbase+j;
        const float ru=sRu[g], rd=sRd[g];
        float aU=fmaxf(duA[j]-ru,0.f)+fmaxf(duB[j]-ru,0.f);
        float aD=fmaxf(ddA[j]-rd,0.f)+fmaxf(ddB[j]-rd,0.f);
#pragma unroll
        for (int off=32; off; off>>=1){ aU+=__shfl_xor(aU,off,64); aD+=__shfl_xor(aD,off,64); }
        if (lane==0){ sAccU[g]=aU; sAccD[g]=aD; }
      }
    }
  }
}

extern "C" void kernel_launch(void* const* d_in, const int* in_sizes, int n_in,
                              void* d_out, int out_size, void* d_ws, size_t ws_size,
                              hipStream_t stream) {
  const float* forecast = (const float*)d_in[0];
  const float* omega    = (const float*)d_in[1];
  const float* omin     = (const float*)d_in[2];
  const float* omax     = (const float*)d_in[3];
  const float* eps      = (const float*)d_in[4];
  const float* pmin     = (const float*)d_in[5];
  const float* pmax     = (const float*)d_in[6];
  const float* bG       = (const float*)d_in[7];
  const float* cG       = (const float*)d_in[8];
  float* out = (float*)d_out;
  float* ws  = (float*)d_ws;
  void* args[] = { &forecast, &omega, &omin, &omax, &eps, &pmin, &pmax, &bG, &cG, &out, &ws };
  hipLaunchCooperativeKernel((const void*)dro_kernel, dim3(NBLK), dim3(NTHR),
                             args, 0, stream);
}